// Round 9
// baseline (586.966 us; speedup 1.0000x reference)
//
#include <hip/hip_runtime.h>
#include <math.h>

#define BB   256     // batch
#define NN0  400     // nodes at layer 1
#define NE   79800   // NN0*(NN0-1)/2
#define EPSF 1e-5f

// ---------- device helpers ----------
__device__ __forceinline__ int tri_e(int a, int c) {  // a<c, upper-tri flat index
  return a*(NN0-1) - ((a*(a-1))>>1) + (c - a - 1);
}

__device__ __forceinline__ float wave_sum(float v) {
  #pragma unroll
  for (int o = 32; o > 0; o >>= 1) v += __shfl_xor(v, o, 64);
  return v;
}

// descending bitonic sort (score desc, idx asc == jax.lax.top_k order), 256 threads
__device__ __forceinline__ void bitonic_desc(float* sc, int* si, int P) {
  const int tid = threadIdx.x;
  for (int k = 2; k <= P; k <<= 1) {
    for (int j = k >> 1; j > 0; j >>= 1) {
      __syncthreads();
      for (int i = tid; i < P; i += 256) {
        int ixj = i ^ j;
        if (ixj > i) {
          float a = sc[i], c = sc[ixj];
          int ai = si[i], ci = si[ixj];
          bool bef = (a > c) || (a == c && ai < ci);
          bool sw = ((i & k) == 0) ? !bef : bef;
          if (sw) { sc[i] = c; sc[ixj] = a; si[i] = ci; si[ixj] = ai; }
        }
      }
    }
  }
  __syncthreads();
}

// ---------- K0: init deg=1 (self loop), sacc=0 ----------
__global__ __launch_bounds__(256) void k_init(
    float* __restrict__ deg, float* __restrict__ sacc) {
  const int e = blockIdx.x*256 + threadIdx.x;
  if (e < BB*NN0) { deg[e] = 1.f; sacc[e] = 0.f; }
}

// ---------- K1: dense symmetric tri-matvec, tile-ROW per block ----------
// grid = BB*7; block (b, ti) streams tiles (ti, ti..6): row-sums accumulate in
// LDS across tiles (1 global atomic/row/block), col-sums 1 atomic set/tile.
__global__ __launch_bounds__(256) void k_tri_mv(
    const float* __restrict__ data, const float* __restrict__ disv,
    float* __restrict__ outacc) {
  __shared__ float tile[64][65];
  __shared__ float dI[64], dJ[64];
  __shared__ float rowacc[64];
  const int ti = blockIdx.x % 7, b = blockIdx.x / 7;
  const int i0 = ti*64;
  const int ni = min(64, NN0 - i0);
  const int tid = threadIdx.x;
  const int wave = tid >> 6, lane = tid & 63;
  if (tid < 64) {
    rowacc[tid] = 0.f;
    dI[tid] = (disv ? ((tid < ni) ? disv[(size_t)b*NN0 + i0 + tid] : 0.f) : 1.f);
  }
  const float* __restrict__ drow = data + (size_t)b*NE;
  for (int tj = ti; tj < 7; ++tj) {
    const int j0 = tj*64;
    const int nj = min(64, NN0 - j0);
    __syncthreads();   // previous tile fully consumed
    if (tid < 64) dJ[tid] = (disv ? ((tid < nj) ? disv[(size_t)b*NN0 + j0 + tid] : 0.f) : 1.f);
    #pragma unroll
    for (int k = 0; k < 16; ++k) {
      const int rr = wave*16 + k;
      const int i = i0 + rr, j = j0 + lane;
      float v = 0.f;
      if (rr < ni && lane < nj && j > i) v = drow[tri_e(i, j)];
      tile[rr][lane] = v;
    }
    __syncthreads();
    // row sums -> rowacc
    {
      const int r = tid >> 2, q = tid & 3;
      float s = 0.f;
      #pragma unroll
      for (int c = 0; c < 16; ++c) s += tile[r][q*16 + c] * dJ[q*16 + c];
      s += __shfl_xor(s, 1, 64);
      s += __shfl_xor(s, 2, 64);
      if (q == 0) rowacc[r] += s;     // single writer per r
    }
    // col sums -> global atomic
    {
      const int c = tid >> 2, q = tid & 3;
      float s = 0.f;
      #pragma unroll
      for (int r = 0; r < 16; ++r) s += tile[q*16 + r][c] * dI[q*16 + r];
      s += __shfl_xor(s, 1, 64);
      s += __shfl_xor(s, 2, 64);
      if (q == 0 && c < nj) atomicAdd(&outacc[(size_t)b*NN0 + j0 + c], s);
    }
  }
  __syncthreads();
  if (tid < ni) atomicAdd(&outacc[(size_t)b*NN0 + i0 + tid], rowacc[tid]);
}

// ---------- K1b: dis = rsqrt(deg) ----------
__global__ __launch_bounds__(256) void k_dis(
    const float* __restrict__ deg, float* __restrict__ dis1) {
  const int i = blockIdx.x*256 + threadIdx.x;
  if (i < BB*NN0) dis1[i] = rsqrtf(deg[i]);
}

// ---------- K1d+K2 fused: s1 = dis*(dis+sacc), + BN partials of relu(s*W1+b1) ----------
__global__ __launch_bounds__(256) void k_sfin_stats(
    const float* __restrict__ dis1, const float* __restrict__ sacc,
    const float* __restrict__ W1, const float* __restrict__ b1,
    float* __restrict__ s1, float* __restrict__ part1) {
  __shared__ float sl[256];
  __shared__ float st[64];
  __shared__ float w1s[32], b1s[32];
  const int tid = threadIdx.x;
  const int i = blockIdx.x*256 + tid;
  if (tid < 32) { w1s[tid] = W1[tid]; b1s[tid] = b1[tid]; }
  if (tid < 64) st[tid] = 0.f;
  const float d = dis1[i];
  const float s = d * (d + sacc[i]);
  s1[i] = s;
  sl[tid] = s;
  __syncthreads();
  const int f = tid & 31, sub = tid >> 5;
  const float w = w1s[f], bb = b1s[f];
  float S = 0.f, Q = 0.f;
  #pragma unroll
  for (int k = 0; k < 32; ++k) {
    const float ss = sl[sub*32 + k];
    const float h = fmaxf(ss*w + bb, 0.f);
    S += h; Q += h*h;
  }
  atomicAdd(&st[f], S);
  atomicAdd(&st[32+f], Q);
  __syncthreads();
  if (tid < 64) part1[(size_t)blockIdx.x*64 + tid] = st[tid];
}

__global__ void k_fin1(const float* __restrict__ part1, const float* __restrict__ g1,
                       const float* __restrict__ be1, const float* __restrict__ p1,
                       float* __restrict__ bn1) {
  const int tid = threadIdx.x;        // 64 threads
  float scale = 0.f, shift = 0.f, pv = 0.f;
  if (tid < 32) {
    float S = 0.f, Q = 0.f;
    for (int blk = 0; blk < 400; ++blk) { S += part1[(size_t)blk*64 + tid]; Q += part1[(size_t)blk*64 + 32 + tid]; }
    const float N = 102400.f;
    const float mu = S / N;
    const float var = Q / N - mu*mu;
    const float inv = rsqrtf(var + EPSF);
    scale = inv * g1[tid];
    shift = be1[tid] - mu * scale;
    pv = p1[tid];
  }
  const float pn = sqrtf(wave_sum(pv*pv));
  if (tid < 32) { bn1[tid] = scale; bn1[32+tid] = shift; bn1[64+tid] = scale*pv/pn; }
  float u = (tid < 32) ? shift*pv/pn : 0.f;
  u = wave_sum(u);
  if (tid == 0) bn1[96] = u;
}

// ---------- K3: layer-1 score + top-200 + X2 gather ----------
__global__ __launch_bounds__(256) void k_top1(
    const float* __restrict__ s1, const float* __restrict__ bn1,
    const float* __restrict__ W1, const float* __restrict__ b1,
    int* __restrict__ nodes2, float* __restrict__ X2) {
  __shared__ float sc[512]; __shared__ int si[512];
  __shared__ float sS[NN0];
  __shared__ float tvs[200];
  __shared__ float w1s[32], b1s[32], cfs[32], scs[32], shs[32];
  const int tid = threadIdx.x, b = blockIdx.x;
  if (tid < 32) {
    scs[tid] = bn1[tid]; shs[tid] = bn1[32+tid]; cfs[tid] = bn1[64+tid];
    w1s[tid] = W1[tid]; b1s[tid] = b1[tid];
  }
  __syncthreads();
  const float c0 = bn1[96];
  for (int i = tid; i < 512; i += 256) {
    if (i < NN0) {
      const float s = s1[(size_t)b*NN0 + i];
      sS[i] = s;
      float sco = c0;
      #pragma unroll
      for (int f = 0; f < 32; ++f) sco += fmaxf(s*w1s[f] + b1s[f], 0.f) * cfs[f];
      sc[i] = sco; si[i] = i;
    } else { sc[i] = -INFINITY; si[i] = 0x7fffffff; }
  }
  bitonic_desc(sc, si, 512);
  for (int k = tid; k < 200; k += 256) {
    tvs[k] = tanhf(sc[k]);
    nodes2[b*200 + k] = si[k];
  }
  __syncthreads();
  for (int o = tid; o < 6400; o += 256) {
    const int k = o >> 5, f = o & 31;
    const float s = sS[si[k]];
    const float h = fmaxf(s*w1s[f] + b1s[f], 0.f);
    X2[(size_t)b*6400 + o] = (h*scs[f] + shs[f]) * tvs[k];
  }
}

// ---------- K4: gather A2 (from data, via node ids) + dis2 ----------
__global__ __launch_bounds__(256) void k_gatherA2(
    const float* __restrict__ data, const int* __restrict__ nodes2,
    float* __restrict__ A2, float* __restrict__ dis2) {
  __shared__ int nds[200];
  const int b = blockIdx.x / 50, rg = blockIdx.x % 50;
  const int tid = threadIdx.x;
  if (tid < 200) nds[tid] = nodes2[b*200 + tid];
  __syncthreads();
  const int wave = tid >> 6, lane = tid & 63;
  const int i = rg*4 + wave;
  const int ni = nds[i];
  const float* __restrict__ drow = data + (size_t)b*NE;
  float accd = 0.f;
  for (int j = lane; j < 200; j += 64) {
    float v = 0.f;
    if (j != i) {
      const int nj = nds[j];
      const int a = min(ni, nj), c = max(ni, nj);
      v = drow[tri_e(a, c)];
    }
    A2[((size_t)b*200 + i)*200 + j] = v;
    accd += v;
  }
  accd = wave_sum(accd);
  if (lane == 0) dis2[b*200 + i] = rsqrtf(1.f + accd);
}

// ---------- K5: Z2 = dis2 * (X2 @ W2) ----------
__global__ __launch_bounds__(256) void k_Z2(
    const float* __restrict__ X2, const float* __restrict__ W2,
    const float* __restrict__ dis2, float* __restrict__ Z2) {
  __shared__ __align__(16) float xs[200*32];
  const int tid = threadIdx.x, b = blockIdx.x;
  const int f = tid & 63;
  float wr[32];
  #pragma unroll
  for (int c = 0; c < 32; ++c) wr[c] = W2[c*64 + f];
  for (int t = tid; t < 6400; t += 256) xs[t] = X2[(size_t)b*6400 + t];
  __syncthreads();
  for (int o = tid; o < 12800; o += 256) {
    const int j = o >> 6;
    float acc = 0.f;
    #pragma unroll
    for (int c4 = 0; c4 < 8; ++c4) {
      const float4 x4 = *(const float4*)&xs[(j<<5) + (c4<<2)];
      acc += x4.x*wr[c4*4] + x4.y*wr[c4*4+1] + x4.z*wr[c4*4+2] + x4.w*wr[c4*4+3];
    }
    Z2[(size_t)b*12800 + o] = dis2[b*200 + j] * acc;
  }
}

// ---------- K6: h2 = relu(dis_i*(A2@Z2 + Z2_i) + b2), + BN partials ----------
// grid = BB*4: blockIdx.x = b*4 + p; rows p*64..p*64+63. Strip-staged A+Z (K=40x5).
__global__ __launch_bounds__(256) void k_conv2(
    const float* __restrict__ A2, const float* __restrict__ Z2,
    const float* __restrict__ dis2, const float* __restrict__ b2,
    float* __restrict__ h2g, float* __restrict__ part2) {
  __shared__ __align__(16) float ab[40*64];   // 10.24 KB [js][local row]
  __shared__ __align__(16) float zb[40*64];   // 10.24 KB [js][feat]
  __shared__ float st[128];
  const int tid = threadIdx.x;
  const int b = blockIdx.x >> 2, p = blockIdx.x & 3;
  const int tx = tid & 15, ty = tid >> 4;
  if (tid < 128) st[tid] = 0.f;
  const float4 bv = *(const float4*)&b2[tx<<2];
  float acc[4][4] = {};
  #pragma unroll 1
  for (int j0 = 0; j0 < 200; j0 += 40) {
    __syncthreads();
    for (int t = tid; t < 640; t += 256) {            // zb: Z2 strip
      const int js = t >> 4, f4 = t & 15;
      *(float4*)&zb[(js << 6) + (f4 << 2)] =
        *(const float4*)&Z2[((size_t)b*200 + (j0 + js))*64 + (f4 << 2)];
    }
    for (int t = tid; t < 640; t += 256) {            // ab: A2 col-band as row-band (symmetry)
      const int js = t >> 4, c4l = t & 15;
      const int cg = (p << 6) + (c4l << 2);
      float4 v = make_float4(0.f, 0.f, 0.f, 0.f);
      if (cg < 200)                                    // cg multiple of 4; 200%4==0 → full or none
        v = *(const float4*)&A2[((size_t)b*200 + (j0 + js))*200 + cg];
      *(float4*)&ab[(js << 6) + (c4l << 2)] = v;
    }
    __syncthreads();
    #pragma unroll 2
    for (int js = 0; js < 40; ++js) {
      const float4 a4 = *(const float4*)&ab[(js << 6) + (ty << 2)];
      const float4 z4 = *(const float4*)&zb[(js << 6) + (tx << 2)];
      acc[0][0] += a4.x*z4.x; acc[0][1] += a4.x*z4.y; acc[0][2] += a4.x*z4.z; acc[0][3] += a4.x*z4.w;
      acc[1][0] += a4.y*z4.x; acc[1][1] += a4.y*z4.y; acc[1][2] += a4.y*z4.z; acc[1][3] += a4.y*z4.w;
      acc[2][0] += a4.z*z4.x; acc[2][1] += a4.z*z4.y; acc[2][2] += a4.z*z4.z; acc[2][3] += a4.z*z4.w;
      acc[3][0] += a4.w*z4.x; acc[3][1] += a4.w*z4.y; acc[3][2] += a4.w*z4.z; acc[3][3] += a4.w*z4.w;
    }
  }
  float ss[4] = {0,0,0,0}, qq[4] = {0,0,0,0};
  #pragma unroll
  for (int qr = 0; qr < 4; ++qr) {
    const int r = (p << 6) + (ty << 2) + qr;
    if (r < 200) {
      const float d = dis2[b*200 + r];
      const float4 zi = *(const float4*)&Z2[((size_t)b*200 + r)*64 + (tx << 2)];
      const float h0 = fmaxf(d*(acc[qr][0] + zi.x) + bv.x, 0.f);
      const float h1 = fmaxf(d*(acc[qr][1] + zi.y) + bv.y, 0.f);
      const float h2v = fmaxf(d*(acc[qr][2] + zi.z) + bv.z, 0.f);
      const float h3v = fmaxf(d*(acc[qr][3] + zi.w) + bv.w, 0.f);
      *(float4*)&h2g[((size_t)b*200 + r)*64 + (tx<<2)] = make_float4(h0,h1,h2v,h3v);
      ss[0]+=h0; ss[1]+=h1; ss[2]+=h2v; ss[3]+=h3v;
      qq[0]+=h0*h0; qq[1]+=h1*h1; qq[2]+=h2v*h2v; qq[3]+=h3v*h3v;
    }
  }
  #pragma unroll
  for (int qf = 0; qf < 4; ++qf) {
    atomicAdd(&st[(tx<<2)+qf], ss[qf]);
    atomicAdd(&st[64+(tx<<2)+qf], qq[qf]);
  }
  __syncthreads();
  if (tid < 128) part2[(size_t)blockIdx.x*128 + tid] = st[tid];
}

__global__ void k_fin2(const float* __restrict__ part2, const float* __restrict__ g2,
                       const float* __restrict__ be2, const float* __restrict__ p2,
                       float* __restrict__ bn2) {
  const int f = threadIdx.x;          // 64 threads
  float S = 0.f, Q = 0.f;
  for (int blk = 0; blk < BB*4; ++blk) { S += part2[(size_t)blk*128 + f]; Q += part2[(size_t)blk*128 + 64 + f]; }
  const float N = 51200.f;
  const float mu = S/N, var = Q/N - mu*mu, inv = rsqrtf(var + EPSF);
  const float scale = inv*g2[f], shift = be2[f] - mu*scale;
  const float pv = p2[f];
  const float pn = sqrtf(wave_sum(pv*pv));
  bn2[f] = scale; bn2[64+f] = shift; bn2[128+f] = scale*pv/pn;
  const float u = wave_sum(shift*pv/pn);
  if (f == 0) bn2[192] = u;
}

// ---------- K8: layer-2 score + top-100 + X3 gather ----------
__global__ __launch_bounds__(256) void k_top2(
    const float* __restrict__ h2g, const float* __restrict__ bn2,
    const int* __restrict__ nodes2, int* __restrict__ nodes3, float* __restrict__ X3) {
  __shared__ float sc[256]; __shared__ int si[256];
  const int tid = threadIdx.x, b = blockIdx.x;
  const int wave = tid >> 6, lane = tid & 63;
  const float cf = bn2[128 + lane];
  const float c20 = bn2[192];
  for (int i = wave; i < 200; i += 4) {
    float v = h2g[((size_t)b*200 + i)*64 + lane] * cf;
    v = wave_sum(v);
    if (lane == 0) { sc[i] = v + c20; si[i] = i; }
  }
  if (tid >= 200) { sc[tid] = -INFINITY; si[tid] = 0x7fffffff; }
  bitonic_desc(sc, si, 256);
  const float scale = bn2[lane], shift = bn2[64 + lane];
  for (int o = tid; o < 6400; o += 256) {
    const int k = o >> 6;
    const int idx = si[k];
    const float tv = tanhf(sc[k]);
    X3[(size_t)b*6400 + o] = (h2g[((size_t)b*200 + idx)*64 + lane] * scale + shift) * tv;
  }
  for (int k = tid; k < 100; k += 256) nodes3[b*100 + k] = nodes2[b*200 + si[k]];
}

// ---------- K9: gather A3 + dis3 ----------
__global__ __launch_bounds__(256) void k_gatherA3(
    const float* __restrict__ data, const int* __restrict__ nodes3,
    float* __restrict__ A3, float* __restrict__ dis3) {
  __shared__ int nds[100];
  const int b = blockIdx.x / 25, rg = blockIdx.x % 25;
  const int tid = threadIdx.x;
  if (tid < 100) nds[tid] = nodes3[b*100 + tid];
  __syncthreads();
  const int wave = tid >> 6, lane = tid & 63;
  const int i = rg*4 + wave;
  const int ni = nds[i];
  const float* __restrict__ drow = data + (size_t)b*NE;
  float accd = 0.f;
  for (int j = lane; j < 100; j += 64) {
    float v = 0.f;
    if (j != i) {
      const int nj = nds[j];
      const int a = min(ni, nj), c = max(ni, nj);
      v = drow[tri_e(a, c)];
    }
    A3[((size_t)b*100 + i)*100 + j] = v;
    accd += v;
  }
  accd = wave_sum(accd);
  if (lane == 0) dis3[b*100 + i] = rsqrtf(1.f + accd);
}

// ---------- K10: Z3 = dis3 * (X3 @ W3) ----------
__global__ __launch_bounds__(256) void k_Z3(
    const float* __restrict__ X3, const float* __restrict__ W3,
    const float* __restrict__ dis3, float* __restrict__ Z3) {
  __shared__ __align__(16) float xs[100*64];
  const int tid = threadIdx.x, b = blockIdx.x;
  const int f = tid & 127;
  float wr[64];
  #pragma unroll
  for (int c = 0; c < 64; ++c) wr[c] = W3[c*128 + f];
  for (int t = tid; t < 6400; t += 256) xs[t] = X3[(size_t)b*6400 + t];
  __syncthreads();
  for (int o = tid; o < 12800; o += 256) {
    const int j = o >> 7;
    float acc = 0.f;
    #pragma unroll
    for (int c4 = 0; c4 < 16; ++c4) {
      const float4 x4 = *(const float4*)&xs[(j<<6) + (c4<<2)];
      acc += x4.x*wr[c4*4] + x4.y*wr[c4*4+1] + x4.z*wr[c4*4+2] + x4.w*wr[c4*4+3];
    }
    Z3[(size_t)b*12800 + o] = dis3[b*100 + j] * acc;
  }
}

// ---------- K11: h3 = relu(dis_i*(A3@Z3 + Z3_i) + b3), + BN partials ----------
// ROUND-5 KNOWN-GOOD FORM: grid = BB*4, full z stage (51.2KB) + 4KB A strip.
__global__ __launch_bounds__(256) void k_conv3(
    const float* __restrict__ A3, const float* __restrict__ Z3,
    const float* __restrict__ dis3, const float* __restrict__ b3,
    float* __restrict__ h3g, float* __restrict__ part3) {
  __shared__ __align__(16) float z[100*128];  // 51.2 KB
  __shared__ __align__(16) float ab[32*32];   // 4 KB strip
  __shared__ float st[256];
  const int tid = threadIdx.x;
  const int b = blockIdx.x >> 2, p = blockIdx.x & 3;
  const int tx = tid & 31, ty = tid >> 5;
  for (int t = tid; t < 12800; t += 256) z[t] = Z3[(size_t)b*12800 + t];
  st[tid] = 0.f;
  const float4 bv = *(const float4*)&b3[tx<<2];
  float acc[4][4] = {};
  #pragma unroll 1
  for (int j0 = 0; j0 < 100; j0 += 32) {
    const int nj = (j0 + 32 <= 100) ? 32 : (100 - j0);
    __syncthreads();
    for (int t = tid; t < nj*32; t += 256) {
      const int js = t >> 5, lr = t & 31;
      const int c = (p << 5) + lr;
      ab[t] = (c < 100) ? A3[((size_t)b*100 + (j0 + js))*100 + c] : 0.f;
    }
    __syncthreads();
    for (int js = 0; js < nj; ++js) {
      const float4 a4 = *(const float4*)&ab[(js<<5) + (ty<<2)];
      const float4 z4 = *(const float4*)&z[((j0+js)<<7) + (tx<<2)];
      acc[0][0] += a4.x*z4.x; acc[0][1] += a4.x*z4.y; acc[0][2] += a4.x*z4.z; acc[0][3] += a4.x*z4.w;
      acc[1][0] += a4.y*z4.x; acc[1][1] += a4.y*z4.y; acc[1][2] += a4.y*z4.z; acc[1][3] += a4.y*z4.w;
      acc[2][0] += a4.z*z4.x; acc[2][1] += a4.z*z4.y; acc[2][2] += a4.z*z4.z; acc[2][3] += a4.z*z4.w;
      acc[3][0] += a4.w*z4.x; acc[3][1] += a4.w*z4.y; acc[3][2] += a4.w*z4.z; acc[3][3] += a4.w*z4.w;
    }
  }
  float ss[4] = {0,0,0,0}, qq[4] = {0,0,0,0};
  #pragma unroll
  for (int qr = 0; qr < 4; ++qr) {
    const int r = (p << 5) + (ty << 2) + qr;
    if (r < 100) {
      const float d = dis3[b*100 + r];
      const float4 zi = *(const float4*)&z[(r << 7) + (tx << 2)];
      const float h0 = fmaxf(d*(acc[qr][0] + zi.x) + bv.x, 0.f);
      const float h1 = fmaxf(d*(acc[qr][1] + zi.y) + bv.y, 0.f);
      const float h2v = fmaxf(d*(acc[qr][2] + zi.z) + bv.z, 0.f);
      const float h3v = fmaxf(d*(acc[qr][3] + zi.w) + bv.w, 0.f);
      *(float4*)&h3g[((size_t)b*100 + r)*128 + (tx<<2)] = make_float4(h0,h1,h2v,h3v);
      ss[0]+=h0; ss[1]+=h1; ss[2]+=h2v; ss[3]+=h3v;
      qq[0]+=h0*h0; qq[1]+=h1*h1; qq[2]+=h2v*h2v; qq[3]+=h3v*h3v;
    }
  }
  #pragma unroll
  for (int qf = 0; qf < 4; ++qf) {
    atomicAdd(&st[(tx<<2)+qf], ss[qf]);
    atomicAdd(&st[128+(tx<<2)+qf], qq[qf]);
  }
  __syncthreads();
  part3[(size_t)blockIdx.x*256 + tid] = st[tid];
}

__global__ void k_fin3(const float* __restrict__ part3, const float* __restrict__ g3,
                       const float* __restrict__ be3, const float* __restrict__ p3,
                       float* __restrict__ bn3) {
  __shared__ float red[2];
  const int f = threadIdx.x;          // 128 threads
  const int wv = f >> 6, lane = f & 63;
  float S = 0.f, Q = 0.f;
  for (int blk = 0; blk < BB*4; ++blk) { S += part3[(size_t)blk*256 + f]; Q += part3[(size_t)blk*256 + 128 + f]; }
  const float N = 25600.f;
  const float mu = S/N, var = Q/N - mu*mu, inv = rsqrtf(var + EPSF);
  const float scale = inv*g3[f], shift = be3[f] - mu*scale;
  const float pv = p3[f];
  float t = wave_sum(pv*pv);
  if (lane == 0) red[wv] = t;
  __syncthreads();
  const float pn = sqrtf(red[0] + red[1]);
  bn3[f] = scale; bn3[128+f] = shift; bn3[256+f] = scale*pv/pn;
  float u = wave_sum(shift*pv/pn);
  __syncthreads();
  if (lane == 0) red[wv] = u;
  __syncthreads();
  if (f == 0) bn3[384] = red[0] + red[1];
}

// ---------- K13: layer-3 score + top-50 + fused max-pool output ----------
__global__ __launch_bounds__(256) void k_top3(
    const float* __restrict__ h3g, const float* __restrict__ bn3, float* __restrict__ out) {
  __shared__ float sc[128]; __shared__ int si[128]; __shared__ float tv[64];
  const int tid = threadIdx.x, b = blockIdx.x;
  const int wave = tid >> 6, lane = tid & 63;
  const float clo = bn3[256 + lane], chi = bn3[320 + lane];
  const float c30 = bn3[384];
  for (int i = wave; i < 100; i += 4) {
    const float* hr = h3g + ((size_t)b*100 + i)*128;
    float v = hr[lane]*clo + hr[64 + lane]*chi;
    v = wave_sum(v);
    if (lane == 0) { sc[i] = v + c30; si[i] = i; }
  }
  if (tid >= 100 && tid < 128) { sc[tid] = -INFINITY; si[tid] = 0x7fffffff; }
  bitonic_desc(sc, si, 128);
  if (tid < 50) tv[tid] = tanhf(sc[tid]);
  __syncthreads();
  if (tid < 128) {
    const float scale = bn3[tid], shift = bn3[128 + tid];
    float m = -INFINITY;
    for (int k = 0; k < 50; ++k) {
      const float h = h3g[((size_t)b*100 + si[k])*128 + tid];
      m = fmaxf(m, (h*scale + shift)*tv[k]);
    }
    out[(size_t)b*128 + tid] = m;
  }
}

// ---------- host ----------
extern "C" void kernel_launch(void* const* d_in, const int* in_sizes, int n_in,
                              void* d_out, int out_size, void* d_ws, size_t ws_size,
                              hipStream_t stream) {
  (void)in_sizes; (void)n_in; (void)out_size; (void)ws_size;
  const float* data = (const float*)d_in[0];
  const float* W1 = (const float*)d_in[1];
  const float* b1 = (const float*)d_in[2];
  const float* g1 = (const float*)d_in[3];
  const float* be1 = (const float*)d_in[4];
  const float* p1 = (const float*)d_in[5];
  const float* W2 = (const float*)d_in[6];
  const float* b2 = (const float*)d_in[7];
  const float* g2 = (const float*)d_in[8];
  const float* be2 = (const float*)d_in[9];
  const float* p2 = (const float*)d_in[10];
  const float* W3 = (const float*)d_in[11];
  const float* b3 = (const float*)d_in[12];
  const float* g3 = (const float*)d_in[13];
  const float* be3 = (const float*)d_in[14];
  const float* p3 = (const float*)d_in[15];
  float* out = (float*)d_out;

  char* ws = (char*)d_ws;
  size_t off = 0;
  auto alloc = [&](size_t n) { size_t o = off; off += (n + 255) & ~(size_t)255; return o; };
  float* deg    = (float*)(ws + alloc((size_t)BB*NN0*4));
  float* dis1   = (float*)(ws + alloc((size_t)BB*NN0*4));
  float* sacc   = (float*)(ws + alloc((size_t)BB*NN0*4));
  float* s1     = (float*)(ws + alloc((size_t)BB*NN0*4));
  float* part1  = (float*)(ws + alloc((size_t)400*64*4));
  float* bn1    = (float*)(ws + alloc(128*4));
  int*   nodes2 = (int*)  (ws + alloc((size_t)BB*200*4));
  float* X2     = (float*)(ws + alloc((size_t)BB*6400*4));
  char*  big    =          ws + alloc((size_t)BB*40000*4);   // A2 region, reused
  float* A2     = (float*)big;                                // live until k_conv2
  float* X3     = (float*)big;                                // written after A2 dead
  float* A3     = (float*)(big + (size_t)BB*6400*4);
  float* Z3     = (float*)(big + (size_t)BB*6400*4 + (size_t)BB*10000*4);
  float* dis2   = (float*)(ws + alloc((size_t)BB*200*4));
  float* Z2     = (float*)(ws + alloc((size_t)BB*12800*4));
  float* h2     = (float*)(ws + alloc((size_t)BB*12800*4));
  float* part2  = (float*)(ws + alloc((size_t)BB*4*128*4));
  float* bn2    = (float*)(ws + alloc(256*4));
  int*   nodes3 = (int*)  (ws + alloc((size_t)BB*100*4));
  float* dis3   = (float*)(ws + alloc((size_t)BB*100*4));
  float* h3     = (float*)(ws + alloc((size_t)BB*12800*4));
  float* part3  = (float*)(ws + alloc((size_t)BB*4*256*4));
  float* bn3    = (float*)(ws + alloc(512*4));

  k_init<<<dim3(400), dim3(256), 0, stream>>>(deg, sacc);
  k_tri_mv<<<dim3(BB*7), dim3(256), 0, stream>>>(data, nullptr, deg);
  k_dis<<<dim3(400), dim3(256), 0, stream>>>(deg, dis1);
  k_tri_mv<<<dim3(BB*7), dim3(256), 0, stream>>>(data, dis1, sacc);
  k_sfin_stats<<<dim3(400), dim3(256), 0, stream>>>(dis1, sacc, W1, b1, s1, part1);
  k_fin1<<<dim3(1), dim3(64), 0, stream>>>(part1, g1, be1, p1, bn1);
  k_top1<<<dim3(BB), dim3(256), 0, stream>>>(s1, bn1, W1, b1, nodes2, X2);
  k_gatherA2<<<dim3(BB*50), dim3(256), 0, stream>>>(data, nodes2, A2, dis2);
  k_Z2<<<dim3(BB), dim3(256), 0, stream>>>(X2, W2, dis2, Z2);
  k_conv2<<<dim3(BB*4), dim3(256), 0, stream>>>(A2, Z2, dis2, b2, h2, part2);
  k_fin2<<<dim3(1), dim3(64), 0, stream>>>(part2, g2, be2, p2, bn2);
  k_top2<<<dim3(BB), dim3(256), 0, stream>>>(h2, bn2, nodes2, nodes3, X3);
  k_gatherA3<<<dim3(BB*25), dim3(256), 0, stream>>>(data, nodes3, A3, dis3);
  k_Z3<<<dim3(BB), dim3(256), 0, stream>>>(X3, W3, dis3, Z3);
  k_conv3<<<dim3(BB*4), dim3(256), 0, stream>>>(A3, Z3, dis3, b3, h3, part3);
  k_fin3<<<dim3(1), dim3(128), 0, stream>>>(part3, g3, be3, p3, bn3);
  k_top3<<<dim3(BB), dim3(256), 0, stream>>>(h3, bn3, out);
}

// Round 10
// 540.983 us; speedup vs baseline: 1.0850x; 1.0850x over previous
//
#include <hip/hip_runtime.h>
#include <math.h>

#define BB   256     // batch
#define NN0  400     // nodes at layer 1
#define NE   79800   // NN0*(NN0-1)/2
#define NTIL 28      // 7x7 upper-triangular 64x64 tiles
#define EPSF 1e-5f

// ---------- device helpers ----------
__device__ __forceinline__ int tri_e(int a, int c) {  // a<c, upper-tri flat index
  return a*(NN0-1) - ((a*(a-1))>>1) + (c - a - 1);
}

__device__ __forceinline__ size_t PRI(int b, int ti, int tj, int r) {
  return (((size_t)b*7 + ti)*7 + tj)*64 + r;
}

__device__ __forceinline__ float wave_sum(float v) {
  #pragma unroll
  for (int o = 32; o > 0; o >>= 1) v += __shfl_xor(v, o, 64);
  return v;
}

// descending bitonic sort (score desc, idx asc == jax.lax.top_k order), 256 threads
__device__ __forceinline__ void bitonic_desc(float* sc, int* si, int P) {
  const int tid = threadIdx.x;
  for (int k = 2; k <= P; k <<= 1) {
    for (int j = k >> 1; j > 0; j >>= 1) {
      __syncthreads();
      for (int i = tid; i < P; i += 256) {
        int ixj = i ^ j;
        if (ixj > i) {
          float a = sc[i], c = sc[ixj];
          int ai = si[i], ci = si[ixj];
          bool bef = (a > c) || (a == c && ai < ci);
          bool sw = ((i & k) == 0) ? !bef : bef;
          if (sw) { sc[i] = c; sc[ixj] = a; si[i] = ci; si[ixj] = ai; }
        }
      }
    }
  }
  __syncthreads();
}

// ---------- K1: dense symmetric tri-matvec partials (NO atomics) ----------
// grid = BB*NTIL; one 64x64 tile per block. Row partials -> pr[b][ti][tj][64],
// col partials -> pc[b][ti][tj][64]; every valid slot written by exactly 1 block.
__global__ __launch_bounds__(256) void k_tri_mv(
    const float* __restrict__ data, const float* __restrict__ disv,
    float* __restrict__ pr, float* __restrict__ pc) {
  __shared__ float tile[64][65];
  __shared__ float dI[64], dJ[64];
  const int t = blockIdx.x % NTIL, b = blockIdx.x / NTIL;
  int ti = 0, rem = t;
  while (rem >= 7 - ti) { rem -= 7 - ti; ++ti; }
  const int tj = ti + rem;
  const int i0 = ti*64, j0 = tj*64;
  const int ni = min(64, NN0 - i0);
  const int nj = min(64, NN0 - j0);
  const int tid = threadIdx.x;
  if (disv) {
    if (tid < 64) dI[tid] = (tid < ni) ? disv[(size_t)b*NN0 + i0 + tid] : 0.f;
    else if (tid < 128) { const int c = tid-64; dJ[c] = (c < nj) ? disv[(size_t)b*NN0 + j0 + c] : 0.f; }
  } else {
    if (tid < 64) dI[tid] = (tid < ni) ? 1.f : 0.f;
    else if (tid < 128) dJ[tid-64] = (tid-64 < nj) ? 1.f : 0.f;
  }
  const int wave = tid >> 6, lane = tid & 63;
  const float* __restrict__ drow = data + (size_t)b*NE;
  #pragma unroll
  for (int k = 0; k < 16; ++k) {
    const int rr = wave*16 + k;
    const int i = i0 + rr, j = j0 + lane;
    float v = 0.f;
    if (rr < ni && lane < nj && j > i) v = drow[tri_e(i, j)];
    tile[rr][lane] = v;
  }
  __syncthreads();
  // row partials: pr = sum_c tile[r][c]*dJ[c]
  {
    const int r = tid >> 2, q = tid & 3;
    float s = 0.f;
    #pragma unroll
    for (int c = 0; c < 16; ++c) s += tile[r][q*16 + c] * dJ[q*16 + c];
    s += __shfl_xor(s, 1, 64);
    s += __shfl_xor(s, 2, 64);
    if (q == 0) pr[PRI(b, ti, tj, r)] = s;
  }
  // col partials: pc = sum_r tile[r][c]*dI[r]
  {
    const int c = tid >> 2, q = tid & 3;
    float s = 0.f;
    #pragma unroll
    for (int r = 0; r < 16; ++r) s += tile[q*16 + r][c] * dI[q*16 + r];
    s += __shfl_xor(s, 1, 64);
    s += __shfl_xor(s, 2, 64);
    if (q == 0) pc[PRI(b, ti, tj, c)] = s;
  }
}

// ---------- K1b: reduce deg partials -> dis = rsqrt(1 + sum) ----------
__global__ __launch_bounds__(256) void k_dis_red(
    const float* __restrict__ pr, const float* __restrict__ pc,
    float* __restrict__ dis1) {
  const int i = blockIdx.x*256 + threadIdx.x;   // exactly 400*256 = 102400
  const int b = i / NN0, n = i % NN0;
  const int t = n >> 6, r = n & 63;
  float acc = 1.f;                               // self loop
  for (int tj = t; tj < 7; ++tj) acc += pr[PRI(b, t, tj, r)];
  for (int ti = 0; ti <= t; ++ti) acc += pc[PRI(b, ti, t, r)];
  dis1[i] = rsqrtf(acc);
}

// ---------- K1d+K2 fused: reduce s partials, s1 = dis*(dis+sacc), + BN stats ----------
__global__ __launch_bounds__(256) void k_sfin_stats_red(
    const float* __restrict__ dis1,
    const float* __restrict__ pr, const float* __restrict__ pc,
    const float* __restrict__ W1, const float* __restrict__ b1,
    float* __restrict__ s1, float* __restrict__ part1) {
  __shared__ float sl[256];
  __shared__ float st[64];
  __shared__ float w1s[32], b1s[32];
  const int tid = threadIdx.x;
  const int i = blockIdx.x*256 + tid;
  if (tid < 32) { w1s[tid] = W1[tid]; b1s[tid] = b1[tid]; }
  if (tid < 64) st[tid] = 0.f;
  const int b = i / NN0, n = i % NN0;
  const int t = n >> 6, r = n & 63;
  float sacc = 0.f;
  for (int tj = t; tj < 7; ++tj) sacc += pr[PRI(b, t, tj, r)];
  for (int ti = 0; ti <= t; ++ti) sacc += pc[PRI(b, ti, t, r)];
  const float d = dis1[i];
  const float s = d * (d + sacc);
  s1[i] = s;
  sl[tid] = s;
  __syncthreads();
  const int f = tid & 31, sub = tid >> 5;
  const float w = w1s[f], bb = b1s[f];
  float S = 0.f, Q = 0.f;
  #pragma unroll
  for (int k = 0; k < 32; ++k) {
    const float ss = sl[sub*32 + k];
    const float h = fmaxf(ss*w + bb, 0.f);
    S += h; Q += h*h;
  }
  atomicAdd(&st[f], S);
  atomicAdd(&st[32+f], Q);
  __syncthreads();
  if (tid < 64) part1[(size_t)blockIdx.x*64 + tid] = st[tid];
}

__global__ void k_fin1(const float* __restrict__ part1, const float* __restrict__ g1,
                       const float* __restrict__ be1, const float* __restrict__ p1,
                       float* __restrict__ bn1) {
  const int tid = threadIdx.x;        // 64 threads
  float scale = 0.f, shift = 0.f, pv = 0.f;
  if (tid < 32) {
    float S = 0.f, Q = 0.f;
    for (int blk = 0; blk < 400; ++blk) { S += part1[(size_t)blk*64 + tid]; Q += part1[(size_t)blk*64 + 32 + tid]; }
    const float N = 102400.f;
    const float mu = S / N;
    const float var = Q / N - mu*mu;
    const float inv = rsqrtf(var + EPSF);
    scale = inv * g1[tid];
    shift = be1[tid] - mu * scale;
    pv = p1[tid];
  }
  const float pn = sqrtf(wave_sum(pv*pv));
  if (tid < 32) { bn1[tid] = scale; bn1[32+tid] = shift; bn1[64+tid] = scale*pv/pn; }
  float u = (tid < 32) ? shift*pv/pn : 0.f;
  u = wave_sum(u);
  if (tid == 0) bn1[96] = u;
}

// ---------- K3: layer-1 score + top-200 + X2 gather ----------
__global__ __launch_bounds__(256) void k_top1(
    const float* __restrict__ s1, const float* __restrict__ bn1,
    const float* __restrict__ W1, const float* __restrict__ b1,
    int* __restrict__ nodes2, float* __restrict__ X2) {
  __shared__ float sc[512]; __shared__ int si[512];
  __shared__ float sS[NN0];
  __shared__ float tvs[200];
  __shared__ float w1s[32], b1s[32], cfs[32], scs[32], shs[32];
  const int tid = threadIdx.x, b = blockIdx.x;
  if (tid < 32) {
    scs[tid] = bn1[tid]; shs[tid] = bn1[32+tid]; cfs[tid] = bn1[64+tid];
    w1s[tid] = W1[tid]; b1s[tid] = b1[tid];
  }
  __syncthreads();
  const float c0 = bn1[96];
  for (int i = tid; i < 512; i += 256) {
    if (i < NN0) {
      const float s = s1[(size_t)b*NN0 + i];
      sS[i] = s;
      float sco = c0;
      #pragma unroll
      for (int f = 0; f < 32; ++f) sco += fmaxf(s*w1s[f] + b1s[f], 0.f) * cfs[f];
      sc[i] = sco; si[i] = i;
    } else { sc[i] = -INFINITY; si[i] = 0x7fffffff; }
  }
  bitonic_desc(sc, si, 512);
  for (int k = tid; k < 200; k += 256) {
    tvs[k] = tanhf(sc[k]);
    nodes2[b*200 + k] = si[k];
  }
  __syncthreads();
  for (int o = tid; o < 6400; o += 256) {
    const int k = o >> 5, f = o & 31;
    const float s = sS[si[k]];
    const float h = fmaxf(s*w1s[f] + b1s[f], 0.f);
    X2[(size_t)b*6400 + o] = (h*scs[f] + shs[f]) * tvs[k];
  }
}

// ---------- K4: gather A2 (from data, via node ids) + dis2 ----------
__global__ __launch_bounds__(256) void k_gatherA2(
    const float* __restrict__ data, const int* __restrict__ nodes2,
    float* __restrict__ A2, float* __restrict__ dis2) {
  __shared__ int nds[200];
  const int b = blockIdx.x / 50, rg = blockIdx.x % 50;
  const int tid = threadIdx.x;
  if (tid < 200) nds[tid] = nodes2[b*200 + tid];
  __syncthreads();
  const int wave = tid >> 6, lane = tid & 63;
  const int i = rg*4 + wave;
  const int ni = nds[i];
  const float* __restrict__ drow = data + (size_t)b*NE;
  float accd = 0.f;
  for (int j = lane; j < 200; j += 64) {
    float v = 0.f;
    if (j != i) {
      const int nj = nds[j];
      const int a = min(ni, nj), c = max(ni, nj);
      v = drow[tri_e(a, c)];
    }
    A2[((size_t)b*200 + i)*200 + j] = v;
    accd += v;
  }
  accd = wave_sum(accd);
  if (lane == 0) dis2[b*200 + i] = rsqrtf(1.f + accd);
}

// ---------- K5: Z2 = dis2 * (X2 @ W2) ----------
__global__ __launch_bounds__(256) void k_Z2(
    const float* __restrict__ X2, const float* __restrict__ W2,
    const float* __restrict__ dis2, float* __restrict__ Z2) {
  __shared__ __align__(16) float xs[200*32];
  const int tid = threadIdx.x, b = blockIdx.x;
  const int f = tid & 63;
  float wr[32];
  #pragma unroll
  for (int c = 0; c < 32; ++c) wr[c] = W2[c*64 + f];
  for (int t = tid; t < 6400; t += 256) xs[t] = X2[(size_t)b*6400 + t];
  __syncthreads();
  for (int o = tid; o < 12800; o += 256) {
    const int j = o >> 6;
    float acc = 0.f;
    #pragma unroll
    for (int c4 = 0; c4 < 8; ++c4) {
      const float4 x4 = *(const float4*)&xs[(j<<5) + (c4<<2)];
      acc += x4.x*wr[c4*4] + x4.y*wr[c4*4+1] + x4.z*wr[c4*4+2] + x4.w*wr[c4*4+3];
    }
    Z2[(size_t)b*12800 + o] = dis2[b*200 + j] * acc;
  }
}

// ---------- K6: h2 = relu(dis_i*(A2@Z2 + Z2_i) + b2), + BN partials ----------
// grid = BB*4: blockIdx.x = b*4 + p; rows p*64..p*64+63. Strip-staged A+Z (K=40x5).
__global__ __launch_bounds__(256) void k_conv2(
    const float* __restrict__ A2, const float* __restrict__ Z2,
    const float* __restrict__ dis2, const float* __restrict__ b2,
    float* __restrict__ h2g, float* __restrict__ part2) {
  __shared__ __align__(16) float ab[40*64];   // 10.24 KB [js][local row]
  __shared__ __align__(16) float zb[40*64];   // 10.24 KB [js][feat]
  __shared__ float st[128];
  const int tid = threadIdx.x;
  const int b = blockIdx.x >> 2, p = blockIdx.x & 3;
  const int tx = tid & 15, ty = tid >> 4;
  if (tid < 128) st[tid] = 0.f;
  const float4 bv = *(const float4*)&b2[tx<<2];
  float acc[4][4] = {};
  #pragma unroll 1
  for (int j0 = 0; j0 < 200; j0 += 40) {
    __syncthreads();
    for (int t = tid; t < 640; t += 256) {            // zb: Z2 strip
      const int js = t >> 4, f4 = t & 15;
      *(float4*)&zb[(js << 6) + (f4 << 2)] =
        *(const float4*)&Z2[((size_t)b*200 + (j0 + js))*64 + (f4 << 2)];
    }
    for (int t = tid; t < 640; t += 256) {            // ab: A2 col-band as row-band (symmetry)
      const int js = t >> 4, c4l = t & 15;
      const int cg = (p << 6) + (c4l << 2);
      float4 v = make_float4(0.f, 0.f, 0.f, 0.f);
      if (cg < 200)                                    // cg multiple of 4; 200%4==0 → full or none
        v = *(const float4*)&A2[((size_t)b*200 + (j0 + js))*200 + cg];
      *(float4*)&ab[(js << 6) + (c4l << 2)] = v;
    }
    __syncthreads();
    #pragma unroll 2
    for (int js = 0; js < 40; ++js) {
      const float4 a4 = *(const float4*)&ab[(js << 6) + (ty << 2)];
      const float4 z4 = *(const float4*)&zb[(js << 6) + (tx << 2)];
      acc[0][0] += a4.x*z4.x; acc[0][1] += a4.x*z4.y; acc[0][2] += a4.x*z4.z; acc[0][3] += a4.x*z4.w;
      acc[1][0] += a4.y*z4.x; acc[1][1] += a4.y*z4.y; acc[1][2] += a4.y*z4.z; acc[1][3] += a4.y*z4.w;
      acc[2][0] += a4.z*z4.x; acc[2][1] += a4.z*z4.y; acc[2][2] += a4.z*z4.z; acc[2][3] += a4.z*z4.w;
      acc[3][0] += a4.w*z4.x; acc[3][1] += a4.w*z4.y; acc[3][2] += a4.w*z4.z; acc[3][3] += a4.w*z4.w;
    }
  }
  float ss[4] = {0,0,0,0}, qq[4] = {0,0,0,0};
  #pragma unroll
  for (int qr = 0; qr < 4; ++qr) {
    const int r = (p << 6) + (ty << 2) + qr;
    if (r < 200) {
      const float d = dis2[b*200 + r];
      const float4 zi = *(const float4*)&Z2[((size_t)b*200 + r)*64 + (tx << 2)];
      const float h0 = fmaxf(d*(acc[qr][0] + zi.x) + bv.x, 0.f);
      const float h1 = fmaxf(d*(acc[qr][1] + zi.y) + bv.y, 0.f);
      const float h2v = fmaxf(d*(acc[qr][2] + zi.z) + bv.z, 0.f);
      const float h3v = fmaxf(d*(acc[qr][3] + zi.w) + bv.w, 0.f);
      *(float4*)&h2g[((size_t)b*200 + r)*64 + (tx<<2)] = make_float4(h0,h1,h2v,h3v);
      ss[0]+=h0; ss[1]+=h1; ss[2]+=h2v; ss[3]+=h3v;
      qq[0]+=h0*h0; qq[1]+=h1*h1; qq[2]+=h2v*h2v; qq[3]+=h3v*h3v;
    }
  }
  #pragma unroll
  for (int qf = 0; qf < 4; ++qf) {
    atomicAdd(&st[(tx<<2)+qf], ss[qf]);
    atomicAdd(&st[64+(tx<<2)+qf], qq[qf]);
  }
  __syncthreads();
  if (tid < 128) part2[(size_t)blockIdx.x*128 + tid] = st[tid];
}

__global__ void k_fin2(const float* __restrict__ part2, const float* __restrict__ g2,
                       const float* __restrict__ be2, const float* __restrict__ p2,
                       float* __restrict__ bn2) {
  const int f = threadIdx.x;          // 64 threads
  float S = 0.f, Q = 0.f;
  for (int blk = 0; blk < BB*4; ++blk) { S += part2[(size_t)blk*128 + f]; Q += part2[(size_t)blk*128 + 64 + f]; }
  const float N = 51200.f;
  const float mu = S/N, var = Q/N - mu*mu, inv = rsqrtf(var + EPSF);
  const float scale = inv*g2[f], shift = be2[f] - mu*scale;
  const float pv = p2[f];
  const float pn = sqrtf(wave_sum(pv*pv));
  bn2[f] = scale; bn2[64+f] = shift; bn2[128+f] = scale*pv/pn;
  const float u = wave_sum(shift*pv/pn);
  if (f == 0) bn2[192] = u;
}

// ---------- K8: layer-2 score + top-100 + X3 gather ----------
__global__ __launch_bounds__(256) void k_top2(
    const float* __restrict__ h2g, const float* __restrict__ bn2,
    const int* __restrict__ nodes2, int* __restrict__ nodes3, float* __restrict__ X3) {
  __shared__ float sc[256]; __shared__ int si[256];
  const int tid = threadIdx.x, b = blockIdx.x;
  const int wave = tid >> 6, lane = tid & 63;
  const float cf = bn2[128 + lane];
  const float c20 = bn2[192];
  for (int i = wave; i < 200; i += 4) {
    float v = h2g[((size_t)b*200 + i)*64 + lane] * cf;
    v = wave_sum(v);
    if (lane == 0) { sc[i] = v + c20; si[i] = i; }
  }
  if (tid >= 200) { sc[tid] = -INFINITY; si[tid] = 0x7fffffff; }
  bitonic_desc(sc, si, 256);
  const float scale = bn2[lane], shift = bn2[64 + lane];
  for (int o = tid; o < 6400; o += 256) {
    const int k = o >> 6;
    const int idx = si[k];
    const float tv = tanhf(sc[k]);
    X3[(size_t)b*6400 + o] = (h2g[((size_t)b*200 + idx)*64 + lane] * scale + shift) * tv;
  }
  for (int k = tid; k < 100; k += 256) nodes3[b*100 + k] = nodes2[b*200 + si[k]];
}

// ---------- K9: gather A3 + dis3 ----------
__global__ __launch_bounds__(256) void k_gatherA3(
    const float* __restrict__ data, const int* __restrict__ nodes3,
    float* __restrict__ A3, float* __restrict__ dis3) {
  __shared__ int nds[100];
  const int b = blockIdx.x / 25, rg = blockIdx.x % 25;
  const int tid = threadIdx.x;
  if (tid < 100) nds[tid] = nodes3[b*100 + tid];
  __syncthreads();
  const int wave = tid >> 6, lane = tid & 63;
  const int i = rg*4 + wave;
  const int ni = nds[i];
  const float* __restrict__ drow = data + (size_t)b*NE;
  float accd = 0.f;
  for (int j = lane; j < 100; j += 64) {
    float v = 0.f;
    if (j != i) {
      const int nj = nds[j];
      const int a = min(ni, nj), c = max(ni, nj);
      v = drow[tri_e(a, c)];
    }
    A3[((size_t)b*100 + i)*100 + j] = v;
    accd += v;
  }
  accd = wave_sum(accd);
  if (lane == 0) dis3[b*100 + i] = rsqrtf(1.f + accd);
}

// ---------- K10: Z3 = dis3 * (X3 @ W3) ----------
__global__ __launch_bounds__(256) void k_Z3(
    const float* __restrict__ X3, const float* __restrict__ W3,
    const float* __restrict__ dis3, float* __restrict__ Z3) {
  __shared__ __align__(16) float xs[100*64];
  const int tid = threadIdx.x, b = blockIdx.x;
  const int f = tid & 127;
  float wr[64];
  #pragma unroll
  for (int c = 0; c < 64; ++c) wr[c] = W3[c*128 + f];
  for (int t = tid; t < 6400; t += 256) xs[t] = X3[(size_t)b*6400 + t];
  __syncthreads();
  for (int o = tid; o < 12800; o += 256) {
    const int j = o >> 7;
    float acc = 0.f;
    #pragma unroll
    for (int c4 = 0; c4 < 16; ++c4) {
      const float4 x4 = *(const float4*)&xs[(j<<6) + (c4<<2)];
      acc += x4.x*wr[c4*4] + x4.y*wr[c4*4+1] + x4.z*wr[c4*4+2] + x4.w*wr[c4*4+3];
    }
    Z3[(size_t)b*12800 + o] = dis3[b*100 + j] * acc;
  }
}

// ---------- K11: h3 = relu(dis_i*(A3@Z3 + Z3_i) + b3), + BN partials ----------
// ROUND-5 KNOWN-GOOD FORM: grid = BB*4, full z stage (51.2KB) + 4KB A strip.
__global__ __launch_bounds__(256) void k_conv3(
    const float* __restrict__ A3, const float* __restrict__ Z3,
    const float* __restrict__ dis3, const float* __restrict__ b3,
    float* __restrict__ h3g, float* __restrict__ part3) {
  __shared__ __align__(16) float z[100*128];  // 51.2 KB
  __shared__ __align__(16) float ab[32*32];   // 4 KB strip
  __shared__ float st[256];
  const int tid = threadIdx.x;
  const int b = blockIdx.x >> 2, p = blockIdx.x & 3;
  const int tx = tid & 31, ty = tid >> 5;
  for (int t = tid; t < 12800; t += 256) z[t] = Z3[(size_t)b*12800 + t];
  st[tid] = 0.f;
  const float4 bv = *(const float4*)&b3[tx<<2];
  float acc[4][4] = {};
  #pragma unroll 1
  for (int j0 = 0; j0 < 100; j0 += 32) {
    const int nj = (j0 + 32 <= 100) ? 32 : (100 - j0);
    __syncthreads();
    for (int t = tid; t < nj*32; t += 256) {
      const int js = t >> 5, lr = t & 31;
      const int c = (p << 5) + lr;
      ab[t] = (c < 100) ? A3[((size_t)b*100 + (j0 + js))*100 + c] : 0.f;
    }
    __syncthreads();
    for (int js = 0; js < nj; ++js) {
      const float4 a4 = *(const float4*)&ab[(js<<5) + (ty<<2)];
      const float4 z4 = *(const float4*)&z[((j0+js)<<7) + (tx<<2)];
      acc[0][0] += a4.x*z4.x; acc[0][1] += a4.x*z4.y; acc[0][2] += a4.x*z4.z; acc[0][3] += a4.x*z4.w;
      acc[1][0] += a4.y*z4.x; acc[1][1] += a4.y*z4.y; acc[1][2] += a4.y*z4.z; acc[1][3] += a4.y*z4.w;
      acc[2][0] += a4.z*z4.x; acc[2][1] += a4.z*z4.y; acc[2][2] += a4.z*z4.z; acc[2][3] += a4.z*z4.w;
      acc[3][0] += a4.w*z4.x; acc[3][1] += a4.w*z4.y; acc[3][2] += a4.w*z4.z; acc[3][3] += a4.w*z4.w;
    }
  }
  float ss[4] = {0,0,0,0}, qq[4] = {0,0,0,0};
  #pragma unroll
  for (int qr = 0; qr < 4; ++qr) {
    const int r = (p << 5) + (ty << 2) + qr;
    if (r < 100) {
      const float d = dis3[b*100 + r];
      const float4 zi = *(const float4*)&z[(r << 7) + (tx << 2)];
      const float h0 = fmaxf(d*(acc[qr][0] + zi.x) + bv.x, 0.f);
      const float h1 = fmaxf(d*(acc[qr][1] + zi.y) + bv.y, 0.f);
      const float h2v = fmaxf(d*(acc[qr][2] + zi.z) + bv.z, 0.f);
      const float h3v = fmaxf(d*(acc[qr][3] + zi.w) + bv.w, 0.f);
      *(float4*)&h3g[((size_t)b*100 + r)*128 + (tx<<2)] = make_float4(h0,h1,h2v,h3v);
      ss[0]+=h0; ss[1]+=h1; ss[2]+=h2v; ss[3]+=h3v;
      qq[0]+=h0*h0; qq[1]+=h1*h1; qq[2]+=h2v*h2v; qq[3]+=h3v*h3v;
    }
  }
  #pragma unroll
  for (int qf = 0; qf < 4; ++qf) {
    atomicAdd(&st[(tx<<2)+qf], ss[qf]);
    atomicAdd(&st[128+(tx<<2)+qf], qq[qf]);
  }
  __syncthreads();
  part3[(size_t)blockIdx.x*256 + tid] = st[tid];
}

__global__ void k_fin3(const float* __restrict__ part3, const float* __restrict__ g3,
                       const float* __restrict__ be3, const float* __restrict__ p3,
                       float* __restrict__ bn3) {
  __shared__ float red[2];
  const int f = threadIdx.x;          // 128 threads
  const int wv = f >> 6, lane = f & 63;
  float S = 0.f, Q = 0.f;
  for (int blk = 0; blk < BB*4; ++blk) { S += part3[(size_t)blk*256 + f]; Q += part3[(size_t)blk*256 + 128 + f]; }
  const float N = 25600.f;
  const float mu = S/N, var = Q/N - mu*mu, inv = rsqrtf(var + EPSF);
  const float scale = inv*g3[f], shift = be3[f] - mu*scale;
  const float pv = p3[f];
  float t = wave_sum(pv*pv);
  if (lane == 0) red[wv] = t;
  __syncthreads();
  const float pn = sqrtf(red[0] + red[1]);
  bn3[f] = scale; bn3[128+f] = shift; bn3[256+f] = scale*pv/pn;
  float u = wave_sum(shift*pv/pn);
  __syncthreads();
  if (lane == 0) red[wv] = u;
  __syncthreads();
  if (f == 0) bn3[384] = red[0] + red[1];
}

// ---------- K13: layer-3 score + top-50 + fused max-pool output ----------
__global__ __launch_bounds__(256) void k_top3(
    const float* __restrict__ h3g, const float* __restrict__ bn3, float* __restrict__ out) {
  __shared__ float sc[128]; __shared__ int si[128]; __shared__ float tv[64];
  const int tid = threadIdx.x, b = blockIdx.x;
  const int wave = tid >> 6, lane = tid & 63;
  const float clo = bn3[256 + lane], chi = bn3[320 + lane];
  const float c30 = bn3[384];
  for (int i = wave; i < 100; i += 4) {
    const float* hr = h3g + ((size_t)b*100 + i)*128;
    float v = hr[lane]*clo + hr[64 + lane]*chi;
    v = wave_sum(v);
    if (lane == 0) { sc[i] = v + c30; si[i] = i; }
  }
  if (tid >= 100 && tid < 128) { sc[tid] = -INFINITY; si[tid] = 0x7fffffff; }
  bitonic_desc(sc, si, 128);
  if (tid < 50) tv[tid] = tanhf(sc[tid]);
  __syncthreads();
  if (tid < 128) {
    const float scale = bn3[tid], shift = bn3[128 + tid];
    float m = -INFINITY;
    for (int k = 0; k < 50; ++k) {
      const float h = h3g[((size_t)b*100 + si[k])*128 + tid];
      m = fmaxf(m, (h*scale + shift)*tv[k]);
    }
    out[(size_t)b*128 + tid] = m;
  }
}

// ---------- host ----------
extern "C" void kernel_launch(void* const* d_in, const int* in_sizes, int n_in,
                              void* d_out, int out_size, void* d_ws, size_t ws_size,
                              hipStream_t stream) {
  (void)in_sizes; (void)n_in; (void)out_size; (void)ws_size;
  const float* data = (const float*)d_in[0];
  const float* W1 = (const float*)d_in[1];
  const float* b1 = (const float*)d_in[2];
  const float* g1 = (const float*)d_in[3];
  const float* be1 = (const float*)d_in[4];
  const float* p1 = (const float*)d_in[5];
  const float* W2 = (const float*)d_in[6];
  const float* b2 = (const float*)d_in[7];
  const float* g2 = (const float*)d_in[8];
  const float* be2 = (const float*)d_in[9];
  const float* p2 = (const float*)d_in[10];
  const float* W3 = (const float*)d_in[11];
  const float* b3 = (const float*)d_in[12];
  const float* g3 = (const float*)d_in[13];
  const float* be3 = (const float*)d_in[14];
  const float* p3 = (const float*)d_in[15];
  float* out = (float*)d_out;

  char* ws = (char*)d_ws;
  size_t off = 0;
  auto alloc = [&](size_t n) { size_t o = off; off += (n + 255) & ~(size_t)255; return o; };
  float* pr     = (float*)(ws + alloc((size_t)BB*49*64*4));
  float* pc     = (float*)(ws + alloc((size_t)BB*49*64*4));
  float* dis1   = (float*)(ws + alloc((size_t)BB*NN0*4));
  float* s1     = (float*)(ws + alloc((size_t)BB*NN0*4));
  float* part1  = (float*)(ws + alloc((size_t)400*64*4));
  float* bn1    = (float*)(ws + alloc(128*4));
  int*   nodes2 = (int*)  (ws + alloc((size_t)BB*200*4));
  float* X2     = (float*)(ws + alloc((size_t)BB*6400*4));
  char*  big    =          ws + alloc((size_t)BB*40000*4);   // A2 region, reused
  float* A2     = (float*)big;                                // live until k_conv2
  float* X3     = (float*)big;                                // written after A2 dead
  float* A3     = (float*)(big + (size_t)BB*6400*4);
  float* Z3     = (float*)(big + (size_t)BB*6400*4 + (size_t)BB*10000*4);
  float* dis2   = (float*)(ws + alloc((size_t)BB*200*4));
  float* Z2     = (float*)(ws + alloc((size_t)BB*12800*4));
  float* h2     = (float*)(ws + alloc((size_t)BB*12800*4));
  float* part2  = (float*)(ws + alloc((size_t)BB*4*128*4));
  float* bn2    = (float*)(ws + alloc(256*4));
  int*   nodes3 = (int*)  (ws + alloc((size_t)BB*100*4));
  float* dis3   = (float*)(ws + alloc((size_t)BB*100*4));
  float* h3     = (float*)(ws + alloc((size_t)BB*12800*4));
  float* part3  = (float*)(ws + alloc((size_t)BB*4*256*4));
  float* bn3    = (float*)(ws + alloc(512*4));

  k_tri_mv<<<dim3(BB*NTIL), dim3(256), 0, stream>>>(data, nullptr, pr, pc);
  k_dis_red<<<dim3(400), dim3(256), 0, stream>>>(pr, pc, dis1);
  k_tri_mv<<<dim3(BB*NTIL), dim3(256), 0, stream>>>(data, dis1, pr, pc);
  k_sfin_stats_red<<<dim3(400), dim3(256), 0, stream>>>(dis1, pr, pc, W1, b1, s1, part1);
  k_fin1<<<dim3(1), dim3(64), 0, stream>>>(part1, g1, be1, p1, bn1);
  k_top1<<<dim3(BB), dim3(256), 0, stream>>>(s1, bn1, W1, b1, nodes2, X2);
  k_gatherA2<<<dim3(BB*50), dim3(256), 0, stream>>>(data, nodes2, A2, dis2);
  k_Z2<<<dim3(BB), dim3(256), 0, stream>>>(X2, W2, dis2, Z2);
  k_conv2<<<dim3(BB*4), dim3(256), 0, stream>>>(A2, Z2, dis2, b2, h2, part2);
  k_fin2<<<dim3(1), dim3(64), 0, stream>>>(part2, g2, be2, p2, bn2);
  k_top2<<<dim3(BB), dim3(256), 0, stream>>>(h2, bn2, nodes2, nodes3, X3);
  k_gatherA3<<<dim3(BB*25), dim3(256), 0, stream>>>(data, nodes3, A3, dis3);
  k_Z3<<<dim3(BB), dim3(256), 0, stream>>>(X3, W3, dis3, Z3);
  k_conv3<<<dim3(BB*4), dim3(256), 0, stream>>>(A3, Z3, dis3, b3, h3, part3);
  k_fin3<<<dim3(1), dim3(128), 0, stream>>>(part3, g3, be3, p3, bn3);
  k_top3<<<dim3(BB), dim3(256), 0, stream>>>(h3, bn3, out);
}

// Round 11
// 529.423 us; speedup vs baseline: 1.1087x; 1.0218x over previous
//
#include <hip/hip_runtime.h>
#include <math.h>

#define BB   256     // batch
#define NN0  400     // nodes at layer 1
#define NE   79800   // NN0*(NN0-1)/2
#define NTIL 28      // 7x7 upper-triangular 64x64 tiles
#define EPSF 1e-5f

// ---------- device helpers ----------
__device__ __forceinline__ int tri_e(int a, int c) {  // a<c, upper-tri flat index
  return a*(NN0-1) - ((a*(a-1))>>1) + (c - a - 1);
}

__device__ __forceinline__ size_t PRI(int b, int ti, int tj, int r) {
  return (((size_t)b*7 + ti)*7 + tj)*64 + r;
}

__device__ __forceinline__ float wave_sum(float v) {
  #pragma unroll
  for (int o = 32; o > 0; o >>= 1) v += __shfl_xor(v, o, 64);
  return v;
}

// descending bitonic sort (score desc, idx asc == jax.lax.top_k order), 256 threads
__device__ __forceinline__ void bitonic_desc(float* sc, int* si, int P) {
  const int tid = threadIdx.x;
  for (int k = 2; k <= P; k <<= 1) {
    for (int j = k >> 1; j > 0; j >>= 1) {
      __syncthreads();
      for (int i = tid; i < P; i += 256) {
        int ixj = i ^ j;
        if (ixj > i) {
          float a = sc[i], c = sc[ixj];
          int ai = si[i], ci = si[ixj];
          bool bef = (a > c) || (a == c && ai < ci);
          bool sw = ((i & k) == 0) ? !bef : bef;
          if (sw) { sc[i] = c; sc[ixj] = a; si[i] = ci; si[ixj] = ai; }
        }
      }
    }
  }
  __syncthreads();
}

// ---------- K1: dense symmetric tri-matvec partials (NO atomics) ----------
__global__ __launch_bounds__(256) void k_tri_mv(
    const float* __restrict__ data, const float* __restrict__ disv,
    float* __restrict__ pr, float* __restrict__ pc) {
  __shared__ float tile[64][65];
  __shared__ float dI[64], dJ[64];
  const int t = blockIdx.x % NTIL, b = blockIdx.x / NTIL;
  int ti = 0, rem = t;
  while (rem >= 7 - ti) { rem -= 7 - ti; ++ti; }
  const int tj = ti + rem;
  const int i0 = ti*64, j0 = tj*64;
  const int ni = min(64, NN0 - i0);
  const int nj = min(64, NN0 - j0);
  const int tid = threadIdx.x;
  if (disv) {
    if (tid < 64) dI[tid] = (tid < ni) ? disv[(size_t)b*NN0 + i0 + tid] : 0.f;
    else if (tid < 128) { const int c = tid-64; dJ[c] = (c < nj) ? disv[(size_t)b*NN0 + j0 + c] : 0.f; }
  } else {
    if (tid < 64) dI[tid] = (tid < ni) ? 1.f : 0.f;
    else if (tid < 128) dJ[tid-64] = (tid-64 < nj) ? 1.f : 0.f;
  }
  const int wave = tid >> 6, lane = tid & 63;
  const float* __restrict__ drow = data + (size_t)b*NE;
  #pragma unroll
  for (int k = 0; k < 16; ++k) {
    const int rr = wave*16 + k;
    const int i = i0 + rr, j = j0 + lane;
    float v = 0.f;
    if (rr < ni && lane < nj && j > i) v = drow[tri_e(i, j)];
    tile[rr][lane] = v;
  }
  __syncthreads();
  {
    const int r = tid >> 2, q = tid & 3;
    float s = 0.f;
    #pragma unroll
    for (int c = 0; c < 16; ++c) s += tile[r][q*16 + c] * dJ[q*16 + c];
    s += __shfl_xor(s, 1, 64);
    s += __shfl_xor(s, 2, 64);
    if (q == 0) pr[PRI(b, ti, tj, r)] = s;
  }
  {
    const int c = tid >> 2, q = tid & 3;
    float s = 0.f;
    #pragma unroll
    for (int r = 0; r < 16; ++r) s += tile[q*16 + r][c] * dI[q*16 + r];
    s += __shfl_xor(s, 1, 64);
    s += __shfl_xor(s, 2, 64);
    if (q == 0) pc[PRI(b, ti, tj, c)] = s;
  }
}

// ---------- K1b: reduce deg partials -> dis = rsqrt(1 + sum) ----------
__global__ __launch_bounds__(256) void k_dis_red(
    const float* __restrict__ pr, const float* __restrict__ pc,
    float* __restrict__ dis1) {
  const int i = blockIdx.x*256 + threadIdx.x;   // exactly 400*256 = 102400
  const int b = i / NN0, n = i % NN0;
  const int t = n >> 6, r = n & 63;
  float acc = 1.f;                               // self loop
  for (int tj = t; tj < 7; ++tj) acc += pr[PRI(b, t, tj, r)];
  for (int ti = 0; ti <= t; ++ti) acc += pc[PRI(b, ti, t, r)];
  dis1[i] = rsqrtf(acc);
}

// ---------- K1d+K2 fused: reduce s partials, s1 = dis*(dis+sacc), + BN stats ----------
__global__ __launch_bounds__(256) void k_sfin_stats_red(
    const float* __restrict__ dis1,
    const float* __restrict__ pr, const float* __restrict__ pc,
    const float* __restrict__ W1, const float* __restrict__ b1,
    float* __restrict__ s1, float* __restrict__ part1) {
  __shared__ float sl[256];
  __shared__ float st[64];
  __shared__ float w1s[32], b1s[32];
  const int tid = threadIdx.x;
  const int i = blockIdx.x*256 + tid;
  if (tid < 32) { w1s[tid] = W1[tid]; b1s[tid] = b1[tid]; }
  if (tid < 64) st[tid] = 0.f;
  const int b = i / NN0, n = i % NN0;
  const int t = n >> 6, r = n & 63;
  float sacc = 0.f;
  for (int tj = t; tj < 7; ++tj) sacc += pr[PRI(b, t, tj, r)];
  for (int ti = 0; ti <= t; ++ti) sacc += pc[PRI(b, ti, t, r)];
  const float d = dis1[i];
  const float s = d * (d + sacc);
  s1[i] = s;
  sl[tid] = s;
  __syncthreads();
  const int f = tid & 31, sub = tid >> 5;
  const float w = w1s[f], bb = b1s[f];
  float S = 0.f, Q = 0.f;
  #pragma unroll
  for (int k = 0; k < 32; ++k) {
    const float ss = sl[sub*32 + k];
    const float h = fmaxf(ss*w + bb, 0.f);
    S += h; Q += h*h;
  }
  atomicAdd(&st[f], S);
  atomicAdd(&st[32+f], Q);
  __syncthreads();
  if (tid < 64) part1[(size_t)blockIdx.x*64 + tid] = st[tid];
}

__global__ void k_fin1(const float* __restrict__ part1, const float* __restrict__ g1,
                       const float* __restrict__ be1, const float* __restrict__ p1,
                       float* __restrict__ bn1) {
  const int tid = threadIdx.x;        // 64 threads
  float scale = 0.f, shift = 0.f, pv = 0.f;
  if (tid < 32) {
    float S = 0.f, Q = 0.f;
    for (int blk = 0; blk < 400; ++blk) { S += part1[(size_t)blk*64 + tid]; Q += part1[(size_t)blk*64 + 32 + tid]; }
    const float N = 102400.f;
    const float mu = S / N;
    const float var = Q / N - mu*mu;
    const float inv = rsqrtf(var + EPSF);
    scale = inv * g1[tid];
    shift = be1[tid] - mu * scale;
    pv = p1[tid];
  }
  const float pn = sqrtf(wave_sum(pv*pv));
  if (tid < 32) { bn1[tid] = scale; bn1[32+tid] = shift; bn1[64+tid] = scale*pv/pn; }
  float u = (tid < 32) ? shift*pv/pn : 0.f;
  u = wave_sum(u);
  if (tid == 0) bn1[96] = u;
}

// ---------- K3: layer-1 score + top-200 + X2 gather + sorted-id permutation ----------
__global__ __launch_bounds__(256) void k_top1(
    const float* __restrict__ s1, const float* __restrict__ bn1,
    const float* __restrict__ W1, const float* __restrict__ b1,
    int* __restrict__ nodes2, int* __restrict__ sperm2, float* __restrict__ X2) {
  __shared__ float sc[512]; __shared__ int si[512];
  __shared__ float sS[NN0];
  __shared__ float tvs[200];
  __shared__ int nds_l[200];
  __shared__ float w1s[32], b1s[32], cfs[32], scs[32], shs[32];
  const int tid = threadIdx.x, b = blockIdx.x;
  if (tid < 32) {
    scs[tid] = bn1[tid]; shs[tid] = bn1[32+tid]; cfs[tid] = bn1[64+tid];
    w1s[tid] = W1[tid]; b1s[tid] = b1[tid];
  }
  __syncthreads();
  const float c0 = bn1[96];
  for (int i = tid; i < 512; i += 256) {
    if (i < NN0) {
      const float s = s1[(size_t)b*NN0 + i];
      sS[i] = s;
      float sco = c0;
      #pragma unroll
      for (int f = 0; f < 32; ++f) sco += fmaxf(s*w1s[f] + b1s[f], 0.f) * cfs[f];
      sc[i] = sco; si[i] = i;
    } else { sc[i] = -INFINITY; si[i] = 0x7fffffff; }
  }
  bitonic_desc(sc, si, 512);
  for (int k = tid; k < 200; k += 256) {
    tvs[k] = tanhf(sc[k]);
    nds_l[k] = si[k];
    nodes2[b*200 + k] = si[k];
  }
  __syncthreads();
  for (int o = tid; o < 6400; o += 256) {
    const int k = o >> 5, f = o & 31;
    const float s = sS[nds_l[k]];
    const float h = fmaxf(s*w1s[f] + b1s[f], 0.f);
    X2[(size_t)b*6400 + o] = (h*scs[f] + shs[f]) * tvs[k];
  }
  // second sort: ascending node id (descending on -id); keys unique
  __syncthreads();
  if (tid < 256) {
    sc[tid] = (tid < 200) ? -(float)nds_l[tid] : -INFINITY;
    si[tid] = (tid < 200) ? tid : 0x7fffffff;
  }
  bitonic_desc(sc, si, 256);
  if (tid < 200) sperm2[b*200 + tid] = si[tid];
}

// ---------- K4: gather A2 (sorted-id order, XCD-swizzled) + dis2 ----------
// grid = BB*50; blockIdx swizzled so all 50 blocks of a batch share blockIdx%8.
__global__ __launch_bounds__(256) void k_gatherA2(
    const float* __restrict__ data, const int* __restrict__ nodes2,
    const int* __restrict__ sperm2, float* __restrict__ A2, float* __restrict__ dis2) {
  __shared__ int nds[200], sp[200], sn[200];
  __shared__ float rowbuf[4][200];
  const int idx = blockIdx.x;
  const int r9 = idx >> 3;
  const int b = (idx & 7)*32 + r9/50;
  const int rg = r9 % 50;
  const int tid = threadIdx.x;
  if (tid < 200) { nds[tid] = nodes2[b*200 + tid]; sp[tid] = sperm2[b*200 + tid]; }
  __syncthreads();
  if (tid < 200) sn[tid] = nds[sp[tid]];
  __syncthreads();
  const int wave = tid >> 6, lane = tid & 63;
  const int i = rg*4 + wave;
  const int ni = nds[i];
  const float* __restrict__ drow = data + (size_t)b*NE;
  float accd = 0.f;
  for (int jj = lane; jj < 200; jj += 64) {
    const int sj = sn[jj];
    float v = 0.f;
    if (sj != ni) {
      const int a = min(ni, sj), c = max(ni, sj);
      v = drow[tri_e(a, c)];
    }
    rowbuf[wave][sp[jj]] = v;
    accd += v;
  }
  __syncthreads();
  for (int j = lane; j < 200; j += 64)
    A2[((size_t)b*200 + i)*200 + j] = rowbuf[wave][j];
  accd = wave_sum(accd);
  if (lane == 0) dis2[b*200 + i] = rsqrtf(1.f + accd);
}

// ---------- K5: Z2 = dis2 * (X2 @ W2) ----------
__global__ __launch_bounds__(256) void k_Z2(
    const float* __restrict__ X2, const float* __restrict__ W2,
    const float* __restrict__ dis2, float* __restrict__ Z2) {
  __shared__ __align__(16) float xs[200*32];
  const int tid = threadIdx.x, b = blockIdx.x;
  const int f = tid & 63;
  float wr[32];
  #pragma unroll
  for (int c = 0; c < 32; ++c) wr[c] = W2[c*64 + f];
  for (int t = tid; t < 6400; t += 256) xs[t] = X2[(size_t)b*6400 + t];
  __syncthreads();
  for (int o = tid; o < 12800; o += 256) {
    const int j = o >> 6;
    float acc = 0.f;
    #pragma unroll
    for (int c4 = 0; c4 < 8; ++c4) {
      const float4 x4 = *(const float4*)&xs[(j<<5) + (c4<<2)];
      acc += x4.x*wr[c4*4] + x4.y*wr[c4*4+1] + x4.z*wr[c4*4+2] + x4.w*wr[c4*4+3];
    }
    Z2[(size_t)b*12800 + o] = dis2[b*200 + j] * acc;
  }
}

// ---------- K6: h2 = relu(dis_i*(A2@Z2 + Z2_i) + b2), + BN partials ----------
__global__ __launch_bounds__(256) void k_conv2(
    const float* __restrict__ A2, const float* __restrict__ Z2,
    const float* __restrict__ dis2, const float* __restrict__ b2,
    float* __restrict__ h2g, float* __restrict__ part2) {
  __shared__ __align__(16) float ab[40*64];   // 10.24 KB [js][local row]
  __shared__ __align__(16) float zb[40*64];   // 10.24 KB [js][feat]
  __shared__ float st[128];
  const int tid = threadIdx.x;
  const int b = blockIdx.x >> 2, p = blockIdx.x & 3;
  const int tx = tid & 15, ty = tid >> 4;
  if (tid < 128) st[tid] = 0.f;
  const float4 bv = *(const float4*)&b2[tx<<2];
  float acc[4][4] = {};
  #pragma unroll 1
  for (int j0 = 0; j0 < 200; j0 += 40) {
    __syncthreads();
    for (int t = tid; t < 640; t += 256) {            // zb: Z2 strip
      const int js = t >> 4, f4 = t & 15;
      *(float4*)&zb[(js << 6) + (f4 << 2)] =
        *(const float4*)&Z2[((size_t)b*200 + (j0 + js))*64 + (f4 << 2)];
    }
    for (int t = tid; t < 640; t += 256) {            // ab: A2 col-band as row-band (symmetry)
      const int js = t >> 4, c4l = t & 15;
      const int cg = (p << 6) + (c4l << 2);
      float4 v = make_float4(0.f, 0.f, 0.f, 0.f);
      if (cg < 200)
        v = *(const float4*)&A2[((size_t)b*200 + (j0 + js))*200 + cg];
      *(float4*)&ab[(js << 6) + (c4l << 2)] = v;
    }
    __syncthreads();
    #pragma unroll 2
    for (int js = 0; js < 40; ++js) {
      const float4 a4 = *(const float4*)&ab[(js << 6) + (ty << 2)];
      const float4 z4 = *(const float4*)&zb[(js << 6) + (tx << 2)];
      acc[0][0] += a4.x*z4.x; acc[0][1] += a4.x*z4.y; acc[0][2] += a4.x*z4.z; acc[0][3] += a4.x*z4.w;
      acc[1][0] += a4.y*z4.x; acc[1][1] += a4.y*z4.y; acc[1][2] += a4.y*z4.z; acc[1][3] += a4.y*z4.w;
      acc[2][0] += a4.z*z4.x; acc[2][1] += a4.z*z4.y; acc[2][2] += a4.z*z4.z; acc[2][3] += a4.z*z4.w;
      acc[3][0] += a4.w*z4.x; acc[3][1] += a4.w*z4.y; acc[3][2] += a4.w*z4.z; acc[3][3] += a4.w*z4.w;
    }
  }
  float ss[4] = {0,0,0,0}, qq[4] = {0,0,0,0};
  #pragma unroll
  for (int qr = 0; qr < 4; ++qr) {
    const int r = (p << 6) + (ty << 2) + qr;
    if (r < 200) {
      const float d = dis2[b*200 + r];
      const float4 zi = *(const float4*)&Z2[((size_t)b*200 + r)*64 + (tx << 2)];
      const float h0 = fmaxf(d*(acc[qr][0] + zi.x) + bv.x, 0.f);
      const float h1 = fmaxf(d*(acc[qr][1] + zi.y) + bv.y, 0.f);
      const float h2v = fmaxf(d*(acc[qr][2] + zi.z) + bv.z, 0.f);
      const float h3v = fmaxf(d*(acc[qr][3] + zi.w) + bv.w, 0.f);
      *(float4*)&h2g[((size_t)b*200 + r)*64 + (tx<<2)] = make_float4(h0,h1,h2v,h3v);
      ss[0]+=h0; ss[1]+=h1; ss[2]+=h2v; ss[3]+=h3v;
      qq[0]+=h0*h0; qq[1]+=h1*h1; qq[2]+=h2v*h2v; qq[3]+=h3v*h3v;
    }
  }
  #pragma unroll
  for (int qf = 0; qf < 4; ++qf) {
    atomicAdd(&st[(tx<<2)+qf], ss[qf]);
    atomicAdd(&st[64+(tx<<2)+qf], qq[qf]);
  }
  __syncthreads();
  if (tid < 128) part2[(size_t)blockIdx.x*128 + tid] = st[tid];
}

__global__ void k_fin2(const float* __restrict__ part2, const float* __restrict__ g2,
                       const float* __restrict__ be2, const float* __restrict__ p2,
                       float* __restrict__ bn2) {
  const int f = threadIdx.x;          // 64 threads
  float S = 0.f, Q = 0.f;
  for (int blk = 0; blk < BB*4; ++blk) { S += part2[(size_t)blk*128 + f]; Q += part2[(size_t)blk*128 + 64 + f]; }
  const float N = 51200.f;
  const float mu = S/N, var = Q/N - mu*mu, inv = rsqrtf(var + EPSF);
  const float scale = inv*g2[f], shift = be2[f] - mu*scale;
  const float pv = p2[f];
  const float pn = sqrtf(wave_sum(pv*pv));
  bn2[f] = scale; bn2[64+f] = shift; bn2[128+f] = scale*pv/pn;
  const float u = wave_sum(shift*pv/pn);
  if (f == 0) bn2[192] = u;
}

// ---------- K8: layer-2 score + top-100 + X3 gather ----------
__global__ __launch_bounds__(256) void k_top2(
    const float* __restrict__ h2g, const float* __restrict__ bn2,
    const int* __restrict__ nodes2, int* __restrict__ nodes3, float* __restrict__ X3) {
  __shared__ float sc[256]; __shared__ int si[256];
  const int tid = threadIdx.x, b = blockIdx.x;
  const int wave = tid >> 6, lane = tid & 63;
  const float cf = bn2[128 + lane];
  const float c20 = bn2[192];
  for (int i = wave; i < 200; i += 4) {
    float v = h2g[((size_t)b*200 + i)*64 + lane] * cf;
    v = wave_sum(v);
    if (lane == 0) { sc[i] = v + c20; si[i] = i; }
  }
  if (tid >= 200) { sc[tid] = -INFINITY; si[tid] = 0x7fffffff; }
  bitonic_desc(sc, si, 256);
  const float scale = bn2[lane], shift = bn2[64 + lane];
  for (int o = tid; o < 6400; o += 256) {
    const int k = o >> 6;
    const int idx = si[k];
    const float tv = tanhf(sc[k]);
    X3[(size_t)b*6400 + o] = (h2g[((size_t)b*200 + idx)*64 + lane] * scale + shift) * tv;
  }
  for (int k = tid; k < 100; k += 256) nodes3[b*100 + k] = nodes2[b*200 + si[k]];
}

// ---------- K9: gather A3 + dis3 ----------
__global__ __launch_bounds__(256) void k_gatherA3(
    const float* __restrict__ data, const int* __restrict__ nodes3,
    float* __restrict__ A3, float* __restrict__ dis3) {
  __shared__ int nds[100];
  const int b = blockIdx.x / 25, rg = blockIdx.x % 25;
  const int tid = threadIdx.x;
  if (tid < 100) nds[tid] = nodes3[b*100 + tid];
  __syncthreads();
  const int wave = tid >> 6, lane = tid & 63;
  const int i = rg*4 + wave;
  const int ni = nds[i];
  const float* __restrict__ drow = data + (size_t)b*NE;
  float accd = 0.f;
  for (int j = lane; j < 100; j += 64) {
    float v = 0.f;
    if (j != i) {
      const int nj = nds[j];
      const int a = min(ni, nj), c = max(ni, nj);
      v = drow[tri_e(a, c)];
    }
    A3[((size_t)b*100 + i)*100 + j] = v;
    accd += v;
  }
  accd = wave_sum(accd);
  if (lane == 0) dis3[b*100 + i] = rsqrtf(1.f + accd);
}

// ---------- K10: Z3 = dis3 * (X3 @ W3) ----------
__global__ __launch_bounds__(256) void k_Z3(
    const float* __restrict__ X3, const float* __restrict__ W3,
    const float* __restrict__ dis3, float* __restrict__ Z3) {
  __shared__ __align__(16) float xs[100*64];
  const int tid = threadIdx.x, b = blockIdx.x;
  const int f = tid & 127;
  float wr[64];
  #pragma unroll
  for (int c = 0; c < 64; ++c) wr[c] = W3[c*128 + f];
  for (int t = tid; t < 6400; t += 256) xs[t] = X3[(size_t)b*6400 + t];
  __syncthreads();
  for (int o = tid; o < 12800; o += 256) {
    const int j = o >> 7;
    float acc = 0.f;
    #pragma unroll
    for (int c4 = 0; c4 < 16; ++c4) {
      const float4 x4 = *(const float4*)&xs[(j<<6) + (c4<<2)];
      acc += x4.x*wr[c4*4] + x4.y*wr[c4*4+1] + x4.z*wr[c4*4+2] + x4.w*wr[c4*4+3];
    }
    Z3[(size_t)b*12800 + o] = dis3[b*100 + j] * acc;
  }
}

// ---------- K11: h3 = relu(dis_i*(A3@Z3 + Z3_i) + b3), + BN partials ----------
__global__ __launch_bounds__(256) void k_conv3(
    const float* __restrict__ A3, const float* __restrict__ Z3,
    const float* __restrict__ dis3, const float* __restrict__ b3,
    float* __restrict__ h3g, float* __restrict__ part3) {
  __shared__ __align__(16) float z[100*128];  // 51.2 KB
  __shared__ __align__(16) float ab[32*32];   // 4 KB strip
  __shared__ float st[256];
  const int tid = threadIdx.x;
  const int b = blockIdx.x >> 2, p = blockIdx.x & 3;
  const int tx = tid & 31, ty = tid >> 5;
  for (int t = tid; t < 12800; t += 256) z[t] = Z3[(size_t)b*12800 + t];
  st[tid] = 0.f;
  const float4 bv = *(const float4*)&b3[tx<<2];
  float acc[4][4] = {};
  #pragma unroll 1
  for (int j0 = 0; j0 < 100; j0 += 32) {
    const int nj = (j0 + 32 <= 100) ? 32 : (100 - j0);
    __syncthreads();
    for (int t = tid; t < nj*32; t += 256) {
      const int js = t >> 5, lr = t & 31;
      const int c = (p << 5) + lr;
      ab[t] = (c < 100) ? A3[((size_t)b*100 + (j0 + js))*100 + c] : 0.f;
    }
    __syncthreads();
    for (int js = 0; js < nj; ++js) {
      const float4 a4 = *(const float4*)&ab[(js<<5) + (ty<<2)];
      const float4 z4 = *(const float4*)&z[((j0+js)<<7) + (tx<<2)];
      acc[0][0] += a4.x*z4.x; acc[0][1] += a4.x*z4.y; acc[0][2] += a4.x*z4.z; acc[0][3] += a4.x*z4.w;
      acc[1][0] += a4.y*z4.x; acc[1][1] += a4.y*z4.y; acc[1][2] += a4.y*z4.z; acc[1][3] += a4.y*z4.w;
      acc[2][0] += a4.z*z4.x; acc[2][1] += a4.z*z4.y; acc[2][2] += a4.z*z4.z; acc[2][3] += a4.z*z4.w;
      acc[3][0] += a4.w*z4.x; acc[3][1] += a4.w*z4.y; acc[3][2] += a4.w*z4.z; acc[3][3] += a4.w*z4.w;
    }
  }
  float ss[4] = {0,0,0,0}, qq[4] = {0,0,0,0};
  #pragma unroll
  for (int qr = 0; qr < 4; ++qr) {
    const int r = (p << 5) + (ty << 2) + qr;
    if (r < 100) {
      const float d = dis3[b*100 + r];
      const float4 zi = *(const float4*)&z[(r << 7) + (tx << 2)];
      const float h0 = fmaxf(d*(acc[qr][0] + zi.x) + bv.x, 0.f);
      const float h1 = fmaxf(d*(acc[qr][1] + zi.y) + bv.y, 0.f);
      const float h2v = fmaxf(d*(acc[qr][2] + zi.z) + bv.z, 0.f);
      const float h3v = fmaxf(d*(acc[qr][3] + zi.w) + bv.w, 0.f);
      *(float4*)&h3g[((size_t)b*100 + r)*128 + (tx<<2)] = make_float4(h0,h1,h2v,h3v);
      ss[0]+=h0; ss[1]+=h1; ss[2]+=h2v; ss[3]+=h3v;
      qq[0]+=h0*h0; qq[1]+=h1*h1; qq[2]+=h2v*h2v; qq[3]+=h3v*h3v;
    }
  }
  #pragma unroll
  for (int qf = 0; qf < 4; ++qf) {
    atomicAdd(&st[(tx<<2)+qf], ss[qf]);
    atomicAdd(&st[128+(tx<<2)+qf], qq[qf]);
  }
  __syncthreads();
  part3[(size_t)blockIdx.x*256 + tid] = st[tid];
}

__global__ void k_fin3(const float* __restrict__ part3, const float* __restrict__ g3,
                       const float* __restrict__ be3, const float* __restrict__ p3,
                       float* __restrict__ bn3) {
  __shared__ float red[2];
  const int f = threadIdx.x;          // 128 threads
  const int wv = f >> 6, lane = f & 63;
  float S = 0.f, Q = 0.f;
  for (int blk = 0; blk < BB*4; ++blk) { S += part3[(size_t)blk*256 + f]; Q += part3[(size_t)blk*256 + 128 + f]; }
  const float N = 25600.f;
  const float mu = S/N, var = Q/N - mu*mu, inv = rsqrtf(var + EPSF);
  const float scale = inv*g3[f], shift = be3[f] - mu*scale;
  const float pv = p3[f];
  float t = wave_sum(pv*pv);
  if (lane == 0) red[wv] = t;
  __syncthreads();
  const float pn = sqrtf(red[0] + red[1]);
  bn3[f] = scale; bn3[128+f] = shift; bn3[256+f] = scale*pv/pn;
  float u = wave_sum(shift*pv/pn);
  __syncthreads();
  if (lane == 0) red[wv] = u;
  __syncthreads();
  if (f == 0) bn3[384] = red[0] + red[1];
}

// ---------- K13: layer-3 score + top-50 + fused max-pool output ----------
__global__ __launch_bounds__(256) void k_top3(
    const float* __restrict__ h3g, const float* __restrict__ bn3, float* __restrict__ out) {
  __shared__ float sc[128]; __shared__ int si[128]; __shared__ float tv[64];
  const int tid = threadIdx.x, b = blockIdx.x;
  const int wave = tid >> 6, lane = tid & 63;
  const float clo = bn3[256 + lane], chi = bn3[320 + lane];
  const float c30 = bn3[384];
  for (int i = wave; i < 100; i += 4) {
    const float* hr = h3g + ((size_t)b*100 + i)*128;
    float v = hr[lane]*clo + hr[64 + lane]*chi;
    v = wave_sum(v);
    if (lane == 0) { sc[i] = v + c30; si[i] = i; }
  }
  if (tid >= 100 && tid < 128) { sc[tid] = -INFINITY; si[tid] = 0x7fffffff; }
  bitonic_desc(sc, si, 128);
  if (tid < 50) tv[tid] = tanhf(sc[tid]);
  __syncthreads();
  if (tid < 128) {
    const float scale = bn3[tid], shift = bn3[128 + tid];
    float m = -INFINITY;
    for (int k = 0; k < 50; ++k) {
      const float h = h3g[((size_t)b*100 + si[k])*128 + tid];
      m = fmaxf(m, (h*scale + shift)*tv[k]);
    }
    out[(size_t)b*128 + tid] = m;
  }
}

// ---------- host ----------
extern "C" void kernel_launch(void* const* d_in, const int* in_sizes, int n_in,
                              void* d_out, int out_size, void* d_ws, size_t ws_size,
                              hipStream_t stream) {
  (void)in_sizes; (void)n_in; (void)out_size; (void)ws_size;
  const float* data = (const float*)d_in[0];
  const float* W1 = (const float*)d_in[1];
  const float* b1 = (const float*)d_in[2];
  const float* g1 = (const float*)d_in[3];
  const float* be1 = (const float*)d_in[4];
  const float* p1 = (const float*)d_in[5];
  const float* W2 = (const float*)d_in[6];
  const float* b2 = (const float*)d_in[7];
  const float* g2 = (const float*)d_in[8];
  const float* be2 = (const float*)d_in[9];
  const float* p2 = (const float*)d_in[10];
  const float* W3 = (const float*)d_in[11];
  const float* b3 = (const float*)d_in[12];
  const float* g3 = (const float*)d_in[13];
  const float* be3 = (const float*)d_in[14];
  const float* p3 = (const float*)d_in[15];
  float* out = (float*)d_out;

  char* ws = (char*)d_ws;
  size_t off = 0;
  auto alloc = [&](size_t n) { size_t o = off; off += (n + 255) & ~(size_t)255; return o; };
  float* pr     = (float*)(ws + alloc((size_t)BB*49*64*4));
  float* pc     = (float*)(ws + alloc((size_t)BB*49*64*4));
  float* dis1   = (float*)(ws + alloc((size_t)BB*NN0*4));
  float* s1     = (float*)(ws + alloc((size_t)BB*NN0*4));
  float* part1  = (float*)(ws + alloc((size_t)400*64*4));
  float* bn1    = (float*)(ws + alloc(128*4));
  int*   nodes2 = (int*)  (ws + alloc((size_t)BB*200*4));
  int*   sperm2 = (int*)  (ws + alloc((size_t)BB*200*4));
  float* X2     = (float*)(ws + alloc((size_t)BB*6400*4));
  char*  big    =          ws + alloc((size_t)BB*40000*4);   // A2 region, reused
  float* A2     = (float*)big;                                // live until k_conv2
  float* X3     = (float*)big;                                // written after A2 dead
  float* A3     = (float*)(big + (size_t)BB*6400*4);
  float* Z3     = (float*)(big + (size_t)BB*6400*4 + (size_t)BB*10000*4);
  float* dis2   = (float*)(ws + alloc((size_t)BB*200*4));
  float* Z2     = (float*)(ws + alloc((size_t)BB*12800*4));
  float* h2     = (float*)(ws + alloc((size_t)BB*12800*4));
  float* part2  = (float*)(ws + alloc((size_t)BB*4*128*4));
  float* bn2    = (float*)(ws + alloc(256*4));
  int*   nodes3 = (int*)  (ws + alloc((size_t)BB*100*4));
  float* dis3   = (float*)(ws + alloc((size_t)BB*100*4));
  float* h3     = (float*)(ws + alloc((size_t)BB*12800*4));
  float* part3  = (float*)(ws + alloc((size_t)BB*4*256*4));
  float* bn3    = (float*)(ws + alloc(512*4));

  k_tri_mv<<<dim3(BB*NTIL), dim3(256), 0, stream>>>(data, nullptr, pr, pc);
  k_dis_red<<<dim3(400), dim3(256), 0, stream>>>(pr, pc, dis1);
  k_tri_mv<<<dim3(BB*NTIL), dim3(256), 0, stream>>>(data, dis1, pr, pc);
  k_sfin_stats_red<<<dim3(400), dim3(256), 0, stream>>>(dis1, pr, pc, W1, b1, s1, part1);
  k_fin1<<<dim3(1), dim3(64), 0, stream>>>(part1, g1, be1, p1, bn1);
  k_top1<<<dim3(BB), dim3(256), 0, stream>>>(s1, bn1, W1, b1, nodes2, sperm2, X2);
  k_gatherA2<<<dim3(BB*50), dim3(256), 0, stream>>>(data, nodes2, sperm2, A2, dis2);
  k_Z2<<<dim3(BB), dim3(256), 0, stream>>>(X2, W2, dis2, Z2);
  k_conv2<<<dim3(BB*4), dim3(256), 0, stream>>>(A2, Z2, dis2, b2, h2, part2);
  k_fin2<<<dim3(1), dim3(64), 0, stream>>>(part2, g2, be2, p2, bn2);
  k_top2<<<dim3(BB), dim3(256), 0, stream>>>(h2, bn2, nodes2, nodes3, X3);
  k_gatherA3<<<dim3(BB*25), dim3(256), 0, stream>>>(data, nodes3, A3, dis3);
  k_Z3<<<dim3(BB), dim3(256), 0, stream>>>(X3, W3, dis3, Z3);
  k_conv3<<<dim3(BB*4), dim3(256), 0, stream>>>(A3, Z3, dis3, b3, h3, part3);
  k_fin3<<<dim3(1), dim3(128), 0, stream>>>(part3, g3, be3, p3, bn3);
  k_top3<<<dim3(BB), dim3(256), 0, stream>>>(h3, bn3, out);
}

// Round 12
// 505.140 us; speedup vs baseline: 1.1620x; 1.0481x over previous
//
#include <hip/hip_runtime.h>
#include <math.h>

#define BB   256     // batch
#define NN0  400     // nodes at layer 1
#define NE   79800   // NN0*(NN0-1)/2
#define NTIL 28      // 7x7 upper-triangular 64x64 tiles
#define EPSF 1e-5f

// ---------- device helpers ----------
__device__ __forceinline__ int tri_e(int a, int c) {  // a<c, upper-tri flat index
  return a*(NN0-1) - ((a*(a-1))>>1) + (c - a - 1);
}

__device__ __forceinline__ size_t PRI(int b, int ti, int tj, int r) {
  return (((size_t)b*7 + ti)*7 + tj)*64 + r;
}

__device__ __forceinline__ float wave_sum(float v) {
  #pragma unroll
  for (int o = 32; o > 0; o >>= 1) v += __shfl_xor(v, o, 64);
  return v;
}

// descending bitonic sort (score desc, idx asc == jax.lax.top_k order), 256 threads
__device__ __forceinline__ void bitonic_desc(float* sc, int* si, int P) {
  const int tid = threadIdx.x;
  for (int k = 2; k <= P; k <<= 1) {
    for (int j = k >> 1; j > 0; j >>= 1) {
      __syncthreads();
      for (int i = tid; i < P; i += 256) {
        int ixj = i ^ j;
        if (ixj > i) {
          float a = sc[i], c = sc[ixj];
          int ai = si[i], ci = si[ixj];
          bool bef = (a > c) || (a == c && ai < ci);
          bool sw = ((i & k) == 0) ? !bef : bef;
          if (sw) { sc[i] = c; sc[ixj] = a; si[i] = ci; si[ixj] = ai; }
        }
      }
    }
  }
  __syncthreads();
}

// ---------- K1: dense symmetric tri-matvec partials (NO atomics) ----------
// grid = BB*7; block q handles tiles {q, q+7, q+14, q+21} (balanced, 4 each),
// register-prefetching tile u+1's loads during tile u's reduce.
__global__ __launch_bounds__(256) void k_tri_mv(
    const float* __restrict__ data, const float* __restrict__ disv,
    float* __restrict__ pr, float* __restrict__ pc) {
  __shared__ float tile[64][65];
  __shared__ float dI[64], dJ[64];
  const int q0 = blockIdx.x % 7, b = blockIdx.x / 7;
  const int tid = threadIdx.x;
  const int wave = tid >> 6, lane = tid & 63;
  const float* __restrict__ drow = data + (size_t)b*NE;
  int ti_a[4], tj_a[4];
  #pragma unroll
  for (int u = 0; u < 4; ++u) {
    int t = q0 + u*7;
    int ti = 0, rem = t;
    while (rem >= 7 - ti) { rem -= 7 - ti; ++ti; }
    ti_a[u] = ti; tj_a[u] = ti + rem;
  }
  float vreg[16];
  float rI = 0.f, rJ = 0.f;
  auto issue = [&](int u) {
    const int i0 = ti_a[u]*64, j0 = tj_a[u]*64;
    const int ni = min(64, NN0 - i0), nj = min(64, NN0 - j0);
    #pragma unroll
    for (int k = 0; k < 16; ++k) {
      const int rr = wave*16 + k;
      const int i = i0 + rr, j = j0 + lane;
      vreg[k] = 0.f;
      if (rr < ni && lane < nj && j > i) vreg[k] = drow[tri_e(i, j)];
    }
    if (disv) {
      if (tid < 64) rI = (tid < ni) ? disv[(size_t)b*NN0 + i0 + tid] : 0.f;
      else if (tid < 128) { const int c = tid-64; rJ = (c < nj) ? disv[(size_t)b*NN0 + j0 + c] : 0.f; }
    } else {
      if (tid < 64) rI = (tid < ni) ? 1.f : 0.f;
      else if (tid < 128) rJ = (tid-64 < nj) ? 1.f : 0.f;
    }
  };
  issue(0);
  #pragma unroll 1
  for (int u = 0; u < 4; ++u) {
    const int ti = ti_a[u], tj = tj_a[u];
    if (u) __syncthreads();           // previous reduce fully consumed tile
    #pragma unroll
    for (int k = 0; k < 16; ++k) tile[wave*16 + k][lane] = vreg[k];
    if (tid < 64) dI[tid] = rI;
    else if (tid < 128) dJ[tid-64] = rJ;
    __syncthreads();
    if (u + 1 < 4) issue(u + 1);      // prefetch next tile during reduce
    // row partials: pr = sum_c tile[r][c]*dJ[c]
    {
      const int r = tid >> 2, q = tid & 3;
      float s = 0.f;
      #pragma unroll
      for (int c = 0; c < 16; ++c) s += tile[r][q*16 + c] * dJ[q*16 + c];
      s += __shfl_xor(s, 1, 64);
      s += __shfl_xor(s, 2, 64);
      if (q == 0) pr[PRI(b, ti, tj, r)] = s;
    }
    // col partials: pc = sum_r tile[r][c]*dI[r]
    {
      const int c = tid >> 2, q = tid & 3;
      float s = 0.f;
      #pragma unroll
      for (int r = 0; r < 16; ++r) s += tile[q*16 + r][c] * dI[q*16 + r];
      s += __shfl_xor(s, 1, 64);
      s += __shfl_xor(s, 2, 64);
      if (q == 0) pc[PRI(b, ti, tj, c)] = s;
    }
  }
}

// ---------- K1b: reduce deg partials -> dis = rsqrt(1 + sum) ----------
__global__ __launch_bounds__(256) void k_dis_red(
    const float* __restrict__ pr, const float* __restrict__ pc,
    float* __restrict__ dis1) {
  const int i = blockIdx.x*256 + threadIdx.x;   // exactly 400*256 = 102400
  const int b = i / NN0, n = i % NN0;
  const int t = n >> 6, r = n & 63;
  float acc = 1.f;                               // self loop
  for (int tj = t; tj < 7; ++tj) acc += pr[PRI(b, t, tj, r)];
  for (int ti = 0; ti <= t; ++ti) acc += pc[PRI(b, ti, t, r)];
  dis1[i] = rsqrtf(acc);
}

// ---------- K1d+K2 fused: reduce s partials, s1 = dis*(dis+sacc), + BN stats ----------
__global__ __launch_bounds__(256) void k_sfin_stats_red(
    const float* __restrict__ dis1,
    const float* __restrict__ pr, const float* __restrict__ pc,
    const float* __restrict__ W1, const float* __restrict__ b1,
    float* __restrict__ s1, float* __restrict__ part1) {
  __shared__ float sl[256];
  __shared__ float st[64];
  __shared__ float w1s[32], b1s[32];
  const int tid = threadIdx.x;
  const int i = blockIdx.x*256 + tid;
  if (tid < 32) { w1s[tid] = W1[tid]; b1s[tid] = b1[tid]; }
  if (tid < 64) st[tid] = 0.f;
  const int b = i / NN0, n = i % NN0;
  const int t = n >> 6, r = n & 63;
  float sacc = 0.f;
  for (int tj = t; tj < 7; ++tj) sacc += pr[PRI(b, t, tj, r)];
  for (int ti = 0; ti <= t; ++ti) sacc += pc[PRI(b, ti, t, r)];
  const float d = dis1[i];
  const float s = d * (d + sacc);
  s1[i] = s;
  sl[tid] = s;
  __syncthreads();
  const int f = tid & 31, sub = tid >> 5;
  const float w = w1s[f], bb = b1s[f];
  float S = 0.f, Q = 0.f;
  #pragma unroll
  for (int k = 0; k < 32; ++k) {
    const float ss = sl[sub*32 + k];
    const float h = fmaxf(ss*w + bb, 0.f);
    S += h; Q += h*h;
  }
  atomicAdd(&st[f], S);
  atomicAdd(&st[32+f], Q);
  __syncthreads();
  if (tid < 64) part1[(size_t)blockIdx.x*64 + tid] = st[tid];
}

__global__ void k_fin1(const float* __restrict__ part1, const float* __restrict__ g1,
                       const float* __restrict__ be1, const float* __restrict__ p1,
                       float* __restrict__ bn1) {
  const int tid = threadIdx.x;        // 64 threads
  float scale = 0.f, shift = 0.f, pv = 0.f;
  if (tid < 32) {
    float S = 0.f, Q = 0.f;
    for (int blk = 0; blk < 400; ++blk) { S += part1[(size_t)blk*64 + tid]; Q += part1[(size_t)blk*64 + 32 + tid]; }
    const float N = 102400.f;
    const float mu = S / N;
    const float var = Q / N - mu*mu;
    const float inv = rsqrtf(var + EPSF);
    scale = inv * g1[tid];
    shift = be1[tid] - mu * scale;
    pv = p1[tid];
  }
  const float pn = sqrtf(wave_sum(pv*pv));
  if (tid < 32) { bn1[tid] = scale; bn1[32+tid] = shift; bn1[64+tid] = scale*pv/pn; }
  float u = (tid < 32) ? shift*pv/pn : 0.f;
  u = wave_sum(u);
  if (tid == 0) bn1[96] = u;
}

// ---------- K3: layer-1 score + top-200 + X2 gather + sorted-id permutation ----------
__global__ __launch_bounds__(256) void k_top1(
    const float* __restrict__ s1, const float* __restrict__ bn1,
    const float* __restrict__ W1, const float* __restrict__ b1,
    int* __restrict__ nodes2, int* __restrict__ sperm2, float* __restrict__ X2) {
  __shared__ float sc[512]; __shared__ int si[512];
  __shared__ float sS[NN0];
  __shared__ float tvs[200];
  __shared__ int nds_l[200];
  __shared__ float w1s[32], b1s[32], cfs[32], scs[32], shs[32];
  const int tid = threadIdx.x, b = blockIdx.x;
  if (tid < 32) {
    scs[tid] = bn1[tid]; shs[tid] = bn1[32+tid]; cfs[tid] = bn1[64+tid];
    w1s[tid] = W1[tid]; b1s[tid] = b1[tid];
  }
  __syncthreads();
  const float c0 = bn1[96];
  for (int i = tid; i < 512; i += 256) {
    if (i < NN0) {
      const float s = s1[(size_t)b*NN0 + i];
      sS[i] = s;
      float sco = c0;
      #pragma unroll
      for (int f = 0; f < 32; ++f) sco += fmaxf(s*w1s[f] + b1s[f], 0.f) * cfs[f];
      sc[i] = sco; si[i] = i;
    } else { sc[i] = -INFINITY; si[i] = 0x7fffffff; }
  }
  bitonic_desc(sc, si, 512);
  for (int k = tid; k < 200; k += 256) {
    tvs[k] = tanhf(sc[k]);
    nds_l[k] = si[k];
    nodes2[b*200 + k] = si[k];
  }
  __syncthreads();
  for (int o = tid; o < 6400; o += 256) {
    const int k = o >> 5, f = o & 31;
    const float s = sS[nds_l[k]];
    const float h = fmaxf(s*w1s[f] + b1s[f], 0.f);
    X2[(size_t)b*6400 + o] = (h*scs[f] + shs[f]) * tvs[k];
  }
  // second sort: ascending node id (descending on -id); keys unique
  __syncthreads();
  if (tid < 256) {
    sc[tid] = (tid < 200) ? -(float)nds_l[tid] : -INFINITY;
    si[tid] = (tid < 200) ? tid : 0x7fffffff;
  }
  bitonic_desc(sc, si, 256);
  if (tid < 200) sperm2[b*200 + tid] = si[tid];
}

// ---------- K4: gather A2 (sorted-id order, XCD-swizzled) + dis2 ----------
// grid = BB*50; blockIdx swizzled so all 50 blocks of a batch share blockIdx%8.
__global__ __launch_bounds__(256) void k_gatherA2(
    const float* __restrict__ data, const int* __restrict__ nodes2,
    const int* __restrict__ sperm2, float* __restrict__ A2, float* __restrict__ dis2) {
  __shared__ int nds[200], sp[200], sn[200];
  __shared__ float rowbuf[4][200];
  const int idx = blockIdx.x;
  const int r9 = idx >> 3;
  const int b = (idx & 7)*32 + r9/50;
  const int rg = r9 % 50;
  const int tid = threadIdx.x;
  if (tid < 200) { nds[tid] = nodes2[b*200 + tid]; sp[tid] = sperm2[b*200 + tid]; }
  __syncthreads();
  if (tid < 200) sn[tid] = nds[sp[tid]];
  __syncthreads();
  const int wave = tid >> 6, lane = tid & 63;
  const int i = rg*4 + wave;
  const int ni = nds[i];
  const float* __restrict__ drow = data + (size_t)b*NE;
  float accd = 0.f;
  for (int jj = lane; jj < 200; jj += 64) {
    const int sj = sn[jj];
    float v = 0.f;
    if (sj != ni) {
      const int a = min(ni, sj), c = max(ni, sj);
      v = drow[tri_e(a, c)];
    }
    rowbuf[wave][sp[jj]] = v;
    accd += v;
  }
  __syncthreads();
  for (int j = lane; j < 200; j += 64)
    A2[((size_t)b*200 + i)*200 + j] = rowbuf[wave][j];
  accd = wave_sum(accd);
  if (lane == 0) dis2[b*200 + i] = rsqrtf(1.f + accd);
}

// ---------- K5: Z2 = dis2 * (X2 @ W2) ----------
__global__ __launch_bounds__(256) void k_Z2(
    const float* __restrict__ X2, const float* __restrict__ W2,
    const float* __restrict__ dis2, float* __restrict__ Z2) {
  __shared__ __align__(16) float xs[200*32];
  const int tid = threadIdx.x, b = blockIdx.x;
  const int f = tid & 63;
  float wr[32];
  #pragma unroll
  for (int c = 0; c < 32; ++c) wr[c] = W2[c*64 + f];
  for (int t = tid; t < 6400; t += 256) xs[t] = X2[(size_t)b*6400 + t];
  __syncthreads();
  for (int o = tid; o < 12800; o += 256) {
    const int j = o >> 6;
    float acc = 0.f;
    #pragma unroll
    for (int c4 = 0; c4 < 8; ++c4) {
      const float4 x4 = *(const float4*)&xs[(j<<5) + (c4<<2)];
      acc += x4.x*wr[c4*4] + x4.y*wr[c4*4+1] + x4.z*wr[c4*4+2] + x4.w*wr[c4*4+3];
    }
    Z2[(size_t)b*12800 + o] = dis2[b*200 + j] * acc;
  }
}

// ---------- K6: h2 = relu(dis_i*(A2@Z2 + Z2_i) + b2), + BN partials ----------
__global__ __launch_bounds__(256) void k_conv2(
    const float* __restrict__ A2, const float* __restrict__ Z2,
    const float* __restrict__ dis2, const float* __restrict__ b2,
    float* __restrict__ h2g, float* __restrict__ part2) {
  __shared__ __align__(16) float ab[40*64];   // 10.24 KB [js][local row]
  __shared__ __align__(16) float zb[40*64];   // 10.24 KB [js][feat]
  __shared__ float st[128];
  const int tid = threadIdx.x;
  const int b = blockIdx.x >> 2, p = blockIdx.x & 3;
  const int tx = tid & 15, ty = tid >> 4;
  if (tid < 128) st[tid] = 0.f;
  const float4 bv = *(const float4*)&b2[tx<<2];
  float acc[4][4] = {};
  #pragma unroll 1
  for (int j0 = 0; j0 < 200; j0 += 40) {
    __syncthreads();
    for (int t = tid; t < 640; t += 256) {            // zb: Z2 strip
      const int js = t >> 4, f4 = t & 15;
      *(float4*)&zb[(js << 6) + (f4 << 2)] =
        *(const float4*)&Z2[((size_t)b*200 + (j0 + js))*64 + (f4 << 2)];
    }
    for (int t = tid; t < 640; t += 256) {            // ab: A2 col-band as row-band (symmetry)
      const int js = t >> 4, c4l = t & 15;
      const int cg = (p << 6) + (c4l << 2);
      float4 v = make_float4(0.f, 0.f, 0.f, 0.f);
      if (cg < 200)
        v = *(const float4*)&A2[((size_t)b*200 + (j0 + js))*200 + cg];
      *(float4*)&ab[(js << 6) + (c4l << 2)] = v;
    }
    __syncthreads();
    #pragma unroll 2
    for (int js = 0; js < 40; ++js) {
      const float4 a4 = *(const float4*)&ab[(js << 6) + (ty << 2)];
      const float4 z4 = *(const float4*)&zb[(js << 6) + (tx << 2)];
      acc[0][0] += a4.x*z4.x; acc[0][1] += a4.x*z4.y; acc[0][2] += a4.x*z4.z; acc[0][3] += a4.x*z4.w;
      acc[1][0] += a4.y*z4.x; acc[1][1] += a4.y*z4.y; acc[1][2] += a4.y*z4.z; acc[1][3] += a4.y*z4.w;
      acc[2][0] += a4.z*z4.x; acc[2][1] += a4.z*z4.y; acc[2][2] += a4.z*z4.z; acc[2][3] += a4.z*z4.w;
      acc[3][0] += a4.w*z4.x; acc[3][1] += a4.w*z4.y; acc[3][2] += a4.w*z4.z; acc[3][3] += a4.w*z4.w;
    }
  }
  float ss[4] = {0,0,0,0}, qq[4] = {0,0,0,0};
  #pragma unroll
  for (int qr = 0; qr < 4; ++qr) {
    const int r = (p << 6) + (ty << 2) + qr;
    if (r < 200) {
      const float d = dis2[b*200 + r];
      const float4 zi = *(const float4*)&Z2[((size_t)b*200 + r)*64 + (tx << 2)];
      const float h0 = fmaxf(d*(acc[qr][0] + zi.x) + bv.x, 0.f);
      const float h1 = fmaxf(d*(acc[qr][1] + zi.y) + bv.y, 0.f);
      const float h2v = fmaxf(d*(acc[qr][2] + zi.z) + bv.z, 0.f);
      const float h3v = fmaxf(d*(acc[qr][3] + zi.w) + bv.w, 0.f);
      *(float4*)&h2g[((size_t)b*200 + r)*64 + (tx<<2)] = make_float4(h0,h1,h2v,h3v);
      ss[0]+=h0; ss[1]+=h1; ss[2]+=h2v; ss[3]+=h3v;
      qq[0]+=h0*h0; qq[1]+=h1*h1; qq[2]+=h2v*h2v; qq[3]+=h3v*h3v;
    }
  }
  #pragma unroll
  for (int qf = 0; qf < 4; ++qf) {
    atomicAdd(&st[(tx<<2)+qf], ss[qf]);
    atomicAdd(&st[64+(tx<<2)+qf], qq[qf]);
  }
  __syncthreads();
  if (tid < 128) part2[(size_t)blockIdx.x*128 + tid] = st[tid];
}

__global__ void k_fin2(const float* __restrict__ part2, const float* __restrict__ g2,
                       const float* __restrict__ be2, const float* __restrict__ p2,
                       float* __restrict__ bn2) {
  const int f = threadIdx.x;          // 64 threads
  float S = 0.f, Q = 0.f;
  for (int blk = 0; blk < BB*4; ++blk) { S += part2[(size_t)blk*128 + f]; Q += part2[(size_t)blk*128 + 64 + f]; }
  const float N = 51200.f;
  const float mu = S/N, var = Q/N - mu*mu, inv = rsqrtf(var + EPSF);
  const float scale = inv*g2[f], shift = be2[f] - mu*scale;
  const float pv = p2[f];
  const float pn = sqrtf(wave_sum(pv*pv));
  bn2[f] = scale; bn2[64+f] = shift; bn2[128+f] = scale*pv/pn;
  const float u = wave_sum(shift*pv/pn);
  if (f == 0) bn2[192] = u;
}

// ---------- K8: layer-2 score + top-100 + X3 gather ----------
__global__ __launch_bounds__(256) void k_top2(
    const float* __restrict__ h2g, const float* __restrict__ bn2,
    const int* __restrict__ nodes2, int* __restrict__ nodes3, float* __restrict__ X3) {
  __shared__ float sc[256]; __shared__ int si[256];
  const int tid = threadIdx.x, b = blockIdx.x;
  const int wave = tid >> 6, lane = tid & 63;
  const float cf = bn2[128 + lane];
  const float c20 = bn2[192];
  for (int i = wave; i < 200; i += 4) {
    float v = h2g[((size_t)b*200 + i)*64 + lane] * cf;
    v = wave_sum(v);
    if (lane == 0) { sc[i] = v + c20; si[i] = i; }
  }
  if (tid >= 200) { sc[tid] = -INFINITY; si[tid] = 0x7fffffff; }
  bitonic_desc(sc, si, 256);
  const float scale = bn2[lane], shift = bn2[64 + lane];
  for (int o = tid; o < 6400; o += 256) {
    const int k = o >> 6;
    const int idx = si[k];
    const float tv = tanhf(sc[k]);
    X3[(size_t)b*6400 + o] = (h2g[((size_t)b*200 + idx)*64 + lane] * scale + shift) * tv;
  }
  for (int k = tid; k < 100; k += 256) nodes3[b*100 + k] = nodes2[b*200 + si[k]];
}

// ---------- K9: gather A3 + dis3 ----------
__global__ __launch_bounds__(256) void k_gatherA3(
    const float* __restrict__ data, const int* __restrict__ nodes3,
    float* __restrict__ A3, float* __restrict__ dis3) {
  __shared__ int nds[100];
  const int b = blockIdx.x / 25, rg = blockIdx.x % 25;
  const int tid = threadIdx.x;
  if (tid < 100) nds[tid] = nodes3[b*100 + tid];
  __syncthreads();
  const int wave = tid >> 6, lane = tid & 63;
  const int i = rg*4 + wave;
  const int ni = nds[i];
  const float* __restrict__ drow = data + (size_t)b*NE;
  float accd = 0.f;
  for (int j = lane; j < 100; j += 64) {
    float v = 0.f;
    if (j != i) {
      const int nj = nds[j];
      const int a = min(ni, nj), c = max(ni, nj);
      v = drow[tri_e(a, c)];
    }
    A3[((size_t)b*100 + i)*100 + j] = v;
    accd += v;
  }
  accd = wave_sum(accd);
  if (lane == 0) dis3[b*100 + i] = rsqrtf(1.f + accd);
}

// ---------- K10: Z3 = dis3 * (X3 @ W3) ----------
__global__ __launch_bounds__(256) void k_Z3(
    const float* __restrict__ X3, const float* __restrict__ W3,
    const float* __restrict__ dis3, float* __restrict__ Z3) {
  __shared__ __align__(16) float xs[100*64];
  const int tid = threadIdx.x, b = blockIdx.x;
  const int f = tid & 127;
  float wr[64];
  #pragma unroll
  for (int c = 0; c < 64; ++c) wr[c] = W3[c*128 + f];
  for (int t = tid; t < 6400; t += 256) xs[t] = X3[(size_t)b*6400 + t];
  __syncthreads();
  for (int o = tid; o < 12800; o += 256) {
    const int j = o >> 7;
    float acc = 0.f;
    #pragma unroll
    for (int c4 = 0; c4 < 16; ++c4) {
      const float4 x4 = *(const float4*)&xs[(j<<6) + (c4<<2)];
      acc += x4.x*wr[c4*4] + x4.y*wr[c4*4+1] + x4.z*wr[c4*4+2] + x4.w*wr[c4*4+3];
    }
    Z3[(size_t)b*12800 + o] = dis3[b*100 + j] * acc;
  }
}

// ---------- K11: h3 = relu(dis_i*(A3@Z3 + Z3_i) + b3), + BN partials ----------
__global__ __launch_bounds__(256) void k_conv3(
    const float* __restrict__ A3, const float* __restrict__ Z3,
    const float* __restrict__ dis3, const float* __restrict__ b3,
    float* __restrict__ h3g, float* __restrict__ part3) {
  __shared__ __align__(16) float z[100*128];  // 51.2 KB
  __shared__ __align__(16) float ab[32*32];   // 4 KB strip
  __shared__ float st[256];
  const int tid = threadIdx.x;
  const int b = blockIdx.x >> 2, p = blockIdx.x & 3;
  const int tx = tid & 31, ty = tid >> 5;
  for (int t = tid; t < 12800; t += 256) z[t] = Z3[(size_t)b*12800 + t];
  st[tid] = 0.f;
  const float4 bv = *(const float4*)&b3[tx<<2];
  float acc[4][4] = {};
  #pragma unroll 1
  for (int j0 = 0; j0 < 100; j0 += 32) {
    const int nj = (j0 + 32 <= 100) ? 32 : (100 - j0);
    __syncthreads();
    for (int t = tid; t < nj*32; t += 256) {
      const int js = t >> 5, lr = t & 31;
      const int c = (p << 5) + lr;
      ab[t] = (c < 100) ? A3[((size_t)b*100 + (j0 + js))*100 + c] : 0.f;
    }
    __syncthreads();
    for (int js = 0; js < nj; ++js) {
      const float4 a4 = *(const float4*)&ab[(js<<5) + (ty<<2)];
      const float4 z4 = *(const float4*)&z[((j0+js)<<7) + (tx<<2)];
      acc[0][0] += a4.x*z4.x; acc[0][1] += a4.x*z4.y; acc[0][2] += a4.x*z4.z; acc[0][3] += a4.x*z4.w;
      acc[1][0] += a4.y*z4.x; acc[1][1] += a4.y*z4.y; acc[1][2] += a4.y*z4.z; acc[1][3] += a4.y*z4.w;
      acc[2][0] += a4.z*z4.x; acc[2][1] += a4.z*z4.y; acc[2][2] += a4.z*z4.z; acc[2][3] += a4.z*z4.w;
      acc[3][0] += a4.w*z4.x; acc[3][1] += a4.w*z4.y; acc[3][2] += a4.w*z4.z; acc[3][3] += a4.w*z4.w;
    }
  }
  float ss[4] = {0,0,0,0}, qq[4] = {0,0,0,0};
  #pragma unroll
  for (int qr = 0; qr < 4; ++qr) {
    const int r = (p << 5) + (ty << 2) + qr;
    if (r < 100) {
      const float d = dis3[b*100 + r];
      const float4 zi = *(const float4*)&z[(r << 7) + (tx << 2)];
      const float h0 = fmaxf(d*(acc[qr][0] + zi.x) + bv.x, 0.f);
      const float h1 = fmaxf(d*(acc[qr][1] + zi.y) + bv.y, 0.f);
      const float h2v = fmaxf(d*(acc[qr][2] + zi.z) + bv.z, 0.f);
      const float h3v = fmaxf(d*(acc[qr][3] + zi.w) + bv.w, 0.f);
      *(float4*)&h3g[((size_t)b*100 + r)*128 + (tx<<2)] = make_float4(h0,h1,h2v,h3v);
      ss[0]+=h0; ss[1]+=h1; ss[2]+=h2v; ss[3]+=h3v;
      qq[0]+=h0*h0; qq[1]+=h1*h1; qq[2]+=h2v*h2v; qq[3]+=h3v*h3v;
    }
  }
  #pragma unroll
  for (int qf = 0; qf < 4; ++qf) {
    atomicAdd(&st[(tx<<2)+qf], ss[qf]);
    atomicAdd(&st[128+(tx<<2)+qf], qq[qf]);
  }
  __syncthreads();
  part3[(size_t)blockIdx.x*256 + tid] = st[tid];
}

__global__ void k_fin3(const float* __restrict__ part3, const float* __restrict__ g3,
                       const float* __restrict__ be3, const float* __restrict__ p3,
                       float* __restrict__ bn3) {
  __shared__ float red[2];
  const int f = threadIdx.x;          // 128 threads
  const int wv = f >> 6, lane = f & 63;
  float S = 0.f, Q = 0.f;
  for (int blk = 0; blk < BB*4; ++blk) { S += part3[(size_t)blk*256 + f]; Q += part3[(size_t)blk*256 + 128 + f]; }
  const float N = 25600.f;
  const float mu = S/N, var = Q/N - mu*mu, inv = rsqrtf(var + EPSF);
  const float scale = inv*g3[f], shift = be3[f] - mu*scale;
  const float pv = p3[f];
  float t = wave_sum(pv*pv);
  if (lane == 0) red[wv] = t;
  __syncthreads();
  const float pn = sqrtf(red[0] + red[1]);
  bn3[f] = scale; bn3[128+f] = shift; bn3[256+f] = scale*pv/pn;
  float u = wave_sum(shift*pv/pn);
  __syncthreads();
  if (lane == 0) red[wv] = u;
  __syncthreads();
  if (f == 0) bn3[384] = red[0] + red[1];
}

// ---------- K13: layer-3 score + top-50 + fused max-pool output ----------
__global__ __launch_bounds__(256) void k_top3(
    const float* __restrict__ h3g, const float* __restrict__ bn3, float* __restrict__ out) {
  __shared__ float sc[128]; __shared__ int si[128]; __shared__ float tv[64];
  const int tid = threadIdx.x, b = blockIdx.x;
  const int wave = tid >> 6, lane = tid & 63;
  const float clo = bn3[256 + lane], chi = bn3[320 + lane];
  const float c30 = bn3[384];
  for (int i = wave; i < 100; i += 4) {
    const float* hr = h3g + ((size_t)b*100 + i)*128;
    float v = hr[lane]*clo + hr[64 + lane]*chi;
    v = wave_sum(v);
    if (lane == 0) { sc[i] = v + c30; si[i] = i; }
  }
  if (tid >= 100 && tid < 128) { sc[tid] = -INFINITY; si[tid] = 0x7fffffff; }
  bitonic_desc(sc, si, 128);
  if (tid < 50) tv[tid] = tanhf(sc[tid]);
  __syncthreads();
  if (tid < 128) {
    const float scale = bn3[tid], shift = bn3[128 + tid];
    float m = -INFINITY;
    for (int k = 0; k < 50; ++k) {
      const float h = h3g[((size_t)b*100 + si[k])*128 + tid];
      m = fmaxf(m, (h*scale + shift)*tv[k]);
    }
    out[(size_t)b*128 + tid] = m;
  }
}

// ---------- host ----------
extern "C" void kernel_launch(void* const* d_in, const int* in_sizes, int n_in,
                              void* d_out, int out_size, void* d_ws, size_t ws_size,
                              hipStream_t stream) {
  (void)in_sizes; (void)n_in; (void)out_size; (void)ws_size;
  const float* data = (const float*)d_in[0];
  const float* W1 = (const float*)d_in[1];
  const float* b1 = (const float*)d_in[2];
  const float* g1 = (const float*)d_in[3];
  const float* be1 = (const float*)d_in[4];
  const float* p1 = (const float*)d_in[5];
  const float* W2 = (const float*)d_in[6];
  const float* b2 = (const float*)d_in[7];
  const float* g2 = (const float*)d_in[8];
  const float* be2 = (const float*)d_in[9];
  const float* p2 = (const float*)d_in[10];
  const float* W3 = (const float*)d_in[11];
  const float* b3 = (const float*)d_in[12];
  const float* g3 = (const float*)d_in[13];
  const float* be3 = (const float*)d_in[14];
  const float* p3 = (const float*)d_in[15];
  float* out = (float*)d_out;

  char* ws = (char*)d_ws;
  size_t off = 0;
  auto alloc = [&](size_t n) { size_t o = off; off += (n + 255) & ~(size_t)255; return o; };
  float* pr     = (float*)(ws + alloc((size_t)BB*49*64*4));
  float* pc     = (float*)(ws + alloc((size_t)BB*49*64*4));
  float* dis1   = (float*)(ws + alloc((size_t)BB*NN0*4));
  float* s1     = (float*)(ws + alloc((size_t)BB*NN0*4));
  float* part1  = (float*)(ws + alloc((size_t)400*64*4));
  float* bn1    = (float*)(ws + alloc(128*4));
  int*   nodes2 = (int*)  (ws + alloc((size_t)BB*200*4));
  int*   sperm2 = (int*)  (ws + alloc((size_t)BB*200*4));
  float* X2     = (float*)(ws + alloc((size_t)BB*6400*4));
  char*  big    =          ws + alloc((size_t)BB*40000*4);   // A2 region, reused
  float* A2     = (float*)big;                                // live until k_conv2
  float* X3     = (float*)big;                                // written after A2 dead
  float* A3     = (float*)(big + (size_t)BB*6400*4);
  float* Z3     = (float*)(big + (size_t)BB*6400*4 + (size_t)BB*10000*4);
  float* dis2   = (float*)(ws + alloc((size_t)BB*200*4));
  float* Z2     = (float*)(ws + alloc((size_t)BB*12800*4));
  float* h2     = (float*)(ws + alloc((size_t)BB*12800*4));
  float* part2  = (float*)(ws + alloc((size_t)BB*4*128*4));
  float* bn2    = (float*)(ws + alloc(256*4));
  int*   nodes3 = (int*)  (ws + alloc((size_t)BB*100*4));
  float* dis3   = (float*)(ws + alloc((size_t)BB*100*4));
  float* h3     = (float*)(ws + alloc((size_t)BB*12800*4));
  float* part3  = (float*)(ws + alloc((size_t)BB*4*256*4));
  float* bn3    = (float*)(ws + alloc(512*4));

  k_tri_mv<<<dim3(BB*7), dim3(256), 0, stream>>>(data, nullptr, pr, pc);
  k_dis_red<<<dim3(400), dim3(256), 0, stream>>>(pr, pc, dis1);
  k_tri_mv<<<dim3(BB*7), dim3(256), 0, stream>>>(data, dis1, pr, pc);
  k_sfin_stats_red<<<dim3(400), dim3(256), 0, stream>>>(dis1, pr, pc, W1, b1, s1, part1);
  k_fin1<<<dim3(1), dim3(64), 0, stream>>>(part1, g1, be1, p1, bn1);
  k_top1<<<dim3(BB), dim3(256), 0, stream>>>(s1, bn1, W1, b1, nodes2, sperm2, X2);
  k_gatherA2<<<dim3(BB*50), dim3(256), 0, stream>>>(data, nodes2, sperm2, A2, dis2);
  k_Z2<<<dim3(BB), dim3(256), 0, stream>>>(X2, W2, dis2, Z2);
  k_conv2<<<dim3(BB*4), dim3(256), 0, stream>>>(A2, Z2, dis2, b2, h2, part2);
  k_fin2<<<dim3(1), dim3(64), 0, stream>>>(part2, g2, be2, p2, bn2);
  k_top2<<<dim3(BB), dim3(256), 0, stream>>>(h2, bn2, nodes2, nodes3, X3);
  k_gatherA3<<<dim3(BB*25), dim3(256), 0, stream>>>(data, nodes3, A3, dis3);
  k_Z3<<<dim3(BB), dim3(256), 0, stream>>>(X3, W3, dis3, Z3);
  k_conv3<<<dim3(BB*4), dim3(256), 0, stream>>>(A3, Z3, dis3, b3, h3, part3);
  k_fin3<<<dim3(1), dim3(128), 0, stream>>>(part3, g3, be3, p3, bn3);
  k_top3<<<dim3(BB), dim3(256), 0, stream>>>(h3, bn3, out);
}